// Round 2
// baseline (2649.718 us; speedup 1.0000x reference)
//
#include <hip/hip_runtime.h>
#include <hip/hip_bf16.h>
#include <math.h>

using bf16 = __hip_bfloat16;
typedef __attribute__((ext_vector_type(8))) short short8;
typedef __attribute__((ext_vector_type(4))) float f32x4;

#define NSEQ   577
#define NBATCH 64
#define NTOK   36928   // 64*577
#define NHEADS 12
#define HDIM   64
#define NP     640     // padded seq len (multiple of 64)
#define CEMB   768
#define CHID   3072

__device__ __forceinline__ bf16 f2bf(float v){ return __float2bfloat16(v); }

// ---------------- weight convert+transpose: src fp32 [R][C] -> dst bf16 [C][R]
__global__ __launch_bounds__(256) void transpose_w(const float* __restrict__ src,
                                                   bf16* __restrict__ dst, int R, int C) {
    long idx = (long)blockIdx.x * 256 + threadIdx.x;
    long total = (long)R * C;
    if (idx < total) {
        int r = (int)(idx / C);
        int c = (int)(idx - (long)r * C);
        dst[(long)c * R + r] = f2bf(src[idx]);
    }
}

// ---------------- LayerNorm: fp32 [rows][768] -> bf16 [rows][768]
__global__ __launch_bounds__(256) void ln_kernel(const float* __restrict__ x,
                                                 const float* __restrict__ gamma,
                                                 const float* __restrict__ beta,
                                                 bf16* __restrict__ out) {
    int row = blockIdx.x;
    const float* xr = x + (size_t)row * CEMB;
    int tid = threadIdx.x;
    float v0 = xr[tid], v1 = xr[tid + 256], v2 = xr[tid + 512];
    float s = v0 + v1 + v2;
    #pragma unroll
    for (int o = 32; o > 0; o >>= 1) s += __shfl_down(s, o);
    __shared__ float red[4];
    if ((tid & 63) == 0) red[tid >> 6] = s;
    __syncthreads();
    float mean = (red[0] + red[1] + red[2] + red[3]) * (1.0f / CEMB);
    float d0 = v0 - mean, d1 = v1 - mean, d2 = v2 - mean;
    float q = d0*d0 + d1*d1 + d2*d2;
    #pragma unroll
    for (int o = 32; o > 0; o >>= 1) q += __shfl_down(q, o);
    __shared__ float red2[4];
    if ((tid & 63) == 0) red2[tid >> 6] = q;
    __syncthreads();
    float var = (red2[0] + red2[1] + red2[2] + red2[3]) * (1.0f / CEMB);
    float rs = rsqrtf(var + 1e-5f);
    bf16* orow = out + (size_t)row * CEMB;
    orow[tid]       = f2bf(d0 * rs * gamma[tid]       + beta[tid]);
    orow[tid + 256] = f2bf(d1 * rs * gamma[tid + 256] + beta[tid + 256]);
    orow[tid + 512] = f2bf(d2 * rs * gamma[tid + 512] + beta[tid + 512]);
}

// ---------------- softmax over rows of S [nrows][NP], valid cols < NSEQ -> P bf16
// Pad rows (garbage) produce finite P (max-subtract bounds exp <= 1); discarded later.
__global__ __launch_bounds__(256) void softmax_kernel(const float* __restrict__ S,
                                                      bf16* __restrict__ P) {
    int row = blockIdx.x * 4 + (threadIdx.x >> 6);
    int lane = threadIdx.x & 63;
    const float* srow = S + (size_t)row * NP;
    bf16* prow = P + (size_t)row * NP;
    float v[10];
    float mx = -1e30f;
    #pragma unroll
    for (int t = 0; t < 10; t++) {
        int j = lane + t * 64;
        float xv = srow[j];
        bool valid = j < NSEQ;
        v[t] = valid ? xv : -1e30f;
        if (valid) mx = fmaxf(mx, xv);
    }
    #pragma unroll
    for (int o = 32; o > 0; o >>= 1) mx = fmaxf(mx, __shfl_xor(mx, o));
    float sum = 0.f;
    #pragma unroll
    for (int t = 0; t < 10; t++) {
        float e = (v[t] > -1e29f) ? __expf(v[t] - mx) : 0.f;
        v[t] = e; sum += e;
    }
    #pragma unroll
    for (int o = 32; o > 0; o >>= 1) sum += __shfl_xor(sum, o);
    float inv = 1.0f / sum;
    #pragma unroll
    for (int t = 0; t < 10; t++) {
        int j = lane + t * 64;
        prow[j] = f2bf(v[t] * inv);   // pad cols exact 0
    }
}

// ---------------- generic bf16 MFMA GEMM, C = A[M,K] * Bt[N,K]^T, with epilogues
#define MODE_S    0
#define MODE_QKV  1
#define MODE_PV   2
#define MODE_PROJ 3
#define MODE_FC1  4
#define MODE_FC2  5

struct GemmParams {
    const bf16* A;
    const bf16* Bt;
    int M, N, K;            // M%64==0, N%64==0, K%32==0 (padded dims)
    int Mreal;              // epilogue row bound (rows >= Mreal skipped)
    long sA, sB, sC;        // batch strides (elements)
    float alpha;
    float* Cf;
    bf16* Cb;
    const float* bias;
    const float* resid;
    bf16* qb; bf16* kb; bf16* vtb;
    int headBase;
};

template<int MODE>
__global__ __launch_bounds__(256) void gemm_bt(GemmParams p) {
    __shared__ bf16 As[64][40];
    __shared__ bf16 Bs[64][40];
    const int tid  = threadIdx.x;
    const int lane = tid & 63;
    const int wave = tid >> 6;
    const int bm = blockIdx.x * 64;
    const int bn = blockIdx.y * 64;
    const int bz = blockIdx.z;
    const bf16* A  = p.A  + (size_t)bz * p.sA;
    const bf16* Bt = p.Bt + (size_t)bz * p.sB;
    const int wr = (wave >> 1) * 32;
    const int wc = (wave & 1) * 32;
    const int lr = tid >> 2;          // 0..63 tile row
    const int lk = (tid & 3) * 8;     // k offset for staging
    const int fr = lane & 15;
    const int fk = (lane >> 4) * 8;

    f32x4 acc[2][2];
    #pragma unroll
    for (int i = 0; i < 2; i++)
        #pragma unroll
        for (int j = 0; j < 2; j++) acc[i][j] = (f32x4){0.f,0.f,0.f,0.f};

    for (int k0 = 0; k0 < p.K; k0 += 32) {
        uint4 av = *reinterpret_cast<const uint4*>(A  + (size_t)(bm + lr) * p.K + k0 + lk);
        uint4 bv = *reinterpret_cast<const uint4*>(Bt + (size_t)(bn + lr) * p.K + k0 + lk);
        __syncthreads();
        *reinterpret_cast<uint4*>(&As[lr][lk]) = av;
        *reinterpret_cast<uint4*>(&Bs[lr][lk]) = bv;
        __syncthreads();
        short8 a0 = *reinterpret_cast<const short8*>(&As[wr + fr][fk]);
        short8 a1 = *reinterpret_cast<const short8*>(&As[wr + 16 + fr][fk]);
        short8 b0 = *reinterpret_cast<const short8*>(&Bs[wc + fr][fk]);
        short8 b1 = *reinterpret_cast<const short8*>(&Bs[wc + 16 + fr][fk]);
        acc[0][0] = __builtin_amdgcn_mfma_f32_16x16x32_bf16(a0, b0, acc[0][0], 0, 0, 0);
        acc[0][1] = __builtin_amdgcn_mfma_f32_16x16x32_bf16(a0, b1, acc[0][1], 0, 0, 0);
        acc[1][0] = __builtin_amdgcn_mfma_f32_16x16x32_bf16(a1, b0, acc[1][0], 0, 0, 0);
        acc[1][1] = __builtin_amdgcn_mfma_f32_16x16x32_bf16(a1, b1, acc[1][1], 0, 0, 0);
    }

    const int fq = (lane >> 4) * 4;
    #pragma unroll
    for (int i = 0; i < 2; i++)
    #pragma unroll
    for (int j = 0; j < 2; j++)
    #pragma unroll
    for (int r = 0; r < 4; r++) {
        int row = bm + wr + i * 16 + fq + r;
        int col = bn + wc + j * 16 + fr;
        float val = acc[i][j][r];
        if (MODE == MODE_S) {
            p.Cf[(size_t)bz * p.sC + (size_t)row * p.N + col] = val * p.alpha;
        } else if (MODE == MODE_QKV) {
            if (row < p.Mreal) {
                int b = row / NSEQ; int n = row - b * NSEQ;    // chunk-local batch
                int which = col / CEMB; int within = col - which * CEMB;
                int hh = within >> 6; int d = within & 63;
                size_t bh = (size_t)(b * NHEADS + hh);
                bf16 ov = f2bf(val);
                if (which == 0)      p.qb [(bh * NP + n) * HDIM + d] = ov;
                else if (which == 1) p.kb [(bh * NP + n) * HDIM + d] = ov;
                else                 p.vtb[(bh * HDIM + d) * NP + n] = ov;
            }
        } else if (MODE == MODE_PV) {
            if (row < NSEQ) {
                int g = p.headBase + bz; int b = g / NHEADS; int hh = g - b * NHEADS;
                p.Cb[((size_t)(b * NSEQ + row)) * CEMB + hh * HDIM + col] = f2bf(val);
            }
        } else if (MODE == MODE_PROJ) {
            if (row < p.Mreal) {
                size_t idx = (size_t)row * p.N + col;
                p.Cf[idx] = val + p.bias[col] + p.resid[idx];
            }
        } else if (MODE == MODE_FC1) {
            if (row < p.Mreal) {
                float t = val + p.bias[col];
                float gl = 0.5f * t * (1.0f + erff(t * 0.70710678118f));
                p.Cb[(size_t)row * p.N + col] = f2bf(gl);
            }
        } else { // MODE_FC2
            if (row < p.Mreal) {
                size_t idx = (size_t)row * p.N + col;
                p.Cf[idx] = val + p.bias[col] + p.resid[idx];
            }
        }
    }
}

extern "C" void kernel_launch(void* const* d_in, const int* in_sizes, int n_in,
                              void* d_out, int out_size, void* d_ws, size_t ws_size,
                              hipStream_t stream) {
    const float* x      = (const float*)d_in[0];
    const float* ln1_g  = (const float*)d_in[1];
    const float* ln1_b  = (const float*)d_in[2];
    const float* w_qkv  = (const float*)d_in[3];   // [768][2304]
    const float* w_proj = (const float*)d_in[4];   // [768][768]
    const float* b_proj = (const float*)d_in[5];
    const float* ln2_g  = (const float*)d_in[6];
    const float* ln2_b  = (const float*)d_in[7];
    const float* w_fc1  = (const float*)d_in[8];   // [768][3072]
    const float* b_fc1  = (const float*)d_in[9];
    const float* w_fc2  = (const float*)d_in[10];  // [3072][768]
    const float* b_fc2  = (const float*)d_in[11];
    float* out = (float*)d_out;

    char* ws = (char*)d_ws;
    auto al = [](size_t b){ return (b + 255) & ~(size_t)255; };
    size_t off = 0;
    auto take = [&](size_t b)->char* { char* p = ws + off; off += al(b); return p; };

    // ---- fixed allocations (always live) ----
    bf16* wqkvT  = (bf16*)take((size_t)2304 * 768 * 2);
    bf16* wprojT = (bf16*)take((size_t)768 * 768 * 2);
    bf16* wfc1T  = (bf16*)take((size_t)3072 * 768 * 2);
    bf16* wfc2T  = (bf16*)take((size_t)768 * 3072 * 2);
    bf16* h      = (bf16*)take((size_t)(NTOK + 64) * CEMB * 2);  // +64 pad rows for chunked reads
    bf16* o      = (bf16*)take((size_t)NTOK * CEMB * 2);
    size_t fixedEnd = off;

    // ---- choose batch-chunk size CB so scratch region fits ws_size ----
    int CB = 16;
    int heads = 0, nMlp = 0, mlpRows = 0, mlpPad = 0;
    size_t qkvB = 0, SB = 0, PB = 0;
    while (true) {
        heads  = CB * NHEADS;
        qkvB   = al((size_t)heads * NP * HDIM * 2);
        SB     = al((size_t)heads * NP * NP * 4);
        PB     = al((size_t)heads * NP * NP * 2);
        nMlp   = 16 / CB;
        mlpRows = NTOK / nMlp;
        mlpPad  = (mlpRows + 63) & ~63;
        size_t gB = al((size_t)mlpPad * CHID * 2);
        size_t attn = 3 * qkvB + SB + PB;
        size_t region = attn > gB ? attn : gB;
        if (fixedEnd + region <= ws_size || CB == 1) break;
        CB >>= 1;
    }
    bf16*  q_c  = (bf16*)(ws + fixedEnd);
    bf16*  k_c  = (bf16*)(ws + fixedEnd + qkvB);
    bf16*  vT_c = (bf16*)(ws + fixedEnd + 2 * qkvB);
    float* S    = (float*)(ws + fixedEnd + 3 * qkvB);
    bf16*  P    = (bf16*)(ws + fixedEnd + 3 * qkvB + SB);
    bf16*  g_c  = (bf16*)(ws + fixedEnd);   // MLP phase reuses the region

    // ---- weights -> bf16 transposed ----
    transpose_w<<<(768 * 2304 + 255) / 256, 256, 0, stream>>>(w_qkv, wqkvT, 768, 2304);
    transpose_w<<<(768 * 768 + 255) / 256, 256, 0, stream>>>(w_proj, wprojT, 768, 768);
    transpose_w<<<(768 * 3072 + 255) / 256, 256, 0, stream>>>(w_fc1, wfc1T, 768, 3072);
    transpose_w<<<(3072 * 768 + 255) / 256, 256, 0, stream>>>(w_fc2, wfc2T, 3072, 768);

    // ---- LN1: x -> h (bf16) ----
    ln_kernel<<<NTOK, 256, 0, stream>>>(x, ln1_g, ln1_b, h);

    // ---- attention, chunks of CB batches ----
    const int qRows = CB * NSEQ;
    const int qPad  = (qRows + 63) & ~63;
    for (int c = 0; c < NBATCH / CB; c++) {
        {   // QKV GEMM for this chunk, scatter epilogue into q_c/k_c/vT_c
            GemmParams p{};
            p.A = h + (size_t)(c * qRows) * CEMB; p.Bt = wqkvT;
            p.M = qPad; p.N = 3 * CEMB; p.K = CEMB; p.Mreal = qRows;
            p.qb = q_c; p.kb = k_c; p.vtb = vT_c;
            gemm_bt<MODE_QKV><<<dim3(qPad / 64, 3 * CEMB / 64, 1), 256, 0, stream>>>(p);
        }
        {   // S = Q K^T * scale
            GemmParams p{};
            p.A = q_c; p.Bt = k_c;
            p.M = NP; p.N = NP; p.K = HDIM; p.Mreal = NP;
            p.sA = (long)NP * HDIM; p.sB = (long)NP * HDIM; p.sC = (long)NP * NP;
            p.alpha = 0.125f; p.Cf = S;
            gemm_bt<MODE_S><<<dim3(NP / 64, NP / 64, heads), 256, 0, stream>>>(p);
        }
        softmax_kernel<<<heads * NP / 4, 256, 0, stream>>>(S, P);
        {   // O = P V  (vT_c is V^T per head)
            GemmParams p{};
            p.A = P; p.Bt = vT_c;
            p.M = NP; p.N = HDIM; p.K = NP; p.Mreal = NP;
            p.sA = (long)NP * NP; p.sB = (long)HDIM * NP; p.sC = 0;
            p.Cb = o; p.headBase = c * heads;
            gemm_bt<MODE_PV><<<dim3(NP / 64, HDIM / 64, heads), 256, 0, stream>>>(p);
        }
    }

    // ---- proj + bias + residual -> out (fp32, acts as x1) ----
    {
        GemmParams p{};
        p.A = o; p.Bt = wprojT;
        p.M = NTOK; p.N = CEMB; p.K = CEMB; p.Mreal = NTOK;
        p.Cf = out; p.bias = b_proj; p.resid = x;
        gemm_bt<MODE_PROJ><<<dim3(NTOK / 64, CEMB / 64, 1), 256, 0, stream>>>(p);
    }

    // ---- LN2: out -> h (bf16) ----
    ln_kernel<<<NTOK, 256, 0, stream>>>(out, ln2_g, ln2_b, h);

    // ---- MLP, chunked over rows ----
    for (int j = 0; j < nMlp; j++) {
        const size_t r0 = (size_t)j * mlpRows;
        {   // FC1 + GELU -> g_c (bf16)
            GemmParams p{};
            p.A = h + r0 * CEMB; p.Bt = wfc1T;
            p.M = mlpPad; p.N = CHID; p.K = CEMB; p.Mreal = mlpRows;
            p.Cb = g_c; p.bias = b_fc1;
            gemm_bt<MODE_FC1><<<dim3(mlpPad / 64, CHID / 64, 1), 256, 0, stream>>>(p);
        }
        {   // FC2 + bias + residual (in-place on out)
            GemmParams p{};
            p.A = g_c; p.Bt = wfc2T;
            p.M = mlpPad; p.N = CEMB; p.K = CHID; p.Mreal = mlpRows;
            p.Cf = out + r0 * CEMB; p.bias = b_fc2; p.resid = out + r0 * CEMB;
            gemm_bt<MODE_FC2><<<dim3(mlpPad / 64, CEMB / 64, 1), 256, 0, stream>>>(p);
        }
    }
}

// Round 3
// 2330.184 us; speedup vs baseline: 1.1371x; 1.1371x over previous
//
#include <hip/hip_runtime.h>
#include <hip/hip_bf16.h>
#include <math.h>

using bf16 = __hip_bfloat16;
typedef __attribute__((ext_vector_type(8))) short short8;
typedef __attribute__((ext_vector_type(4))) float f32x4;

#define NSEQ   577
#define NBATCH 64
#define NTOK   36928   // 64*577
#define NHEADS 12
#define HDIM   64
#define NP     640     // padded seq len (multiple of 128)
#define CEMB   768
#define CHID   3072

__device__ __forceinline__ bf16 f2bf(float v){ return __float2bfloat16(v); }

#define GLOAD_LDS16(gaddr, laddr) \
  __builtin_amdgcn_global_load_lds((__attribute__((address_space(1))) const void*)(gaddr), \
                                   (__attribute__((address_space(3))) void*)(laddr), 16, 0, 0)

// ---------------- weight convert+transpose: src fp32 [R][C] -> dst bf16 [C][R]
__global__ __launch_bounds__(256) void transpose_w(const float* __restrict__ src,
                                                   bf16* __restrict__ dst, int R, int C) {
    long idx = (long)blockIdx.x * 256 + threadIdx.x;
    long total = (long)R * C;
    if (idx < total) {
        int r = (int)(idx / C);
        int c = (int)(idx - (long)r * C);
        dst[(long)c * R + r] = f2bf(src[idx]);
    }
}

// ---------------- LayerNorm: fp32 [rows][768] -> bf16 [rows][768]
__global__ __launch_bounds__(256) void ln_kernel(const float* __restrict__ x,
                                                 const float* __restrict__ gamma,
                                                 const float* __restrict__ beta,
                                                 bf16* __restrict__ out) {
    int row = blockIdx.x;
    const float* xr = x + (size_t)row * CEMB;
    int tid = threadIdx.x;
    float v0 = xr[tid], v1 = xr[tid + 256], v2 = xr[tid + 512];
    float s = v0 + v1 + v2;
    #pragma unroll
    for (int o = 32; o > 0; o >>= 1) s += __shfl_down(s, o);
    __shared__ float red[4];
    if ((tid & 63) == 0) red[tid >> 6] = s;
    __syncthreads();
    float mean = (red[0] + red[1] + red[2] + red[3]) * (1.0f / CEMB);
    float d0 = v0 - mean, d1 = v1 - mean, d2 = v2 - mean;
    float q = d0*d0 + d1*d1 + d2*d2;
    #pragma unroll
    for (int o = 32; o > 0; o >>= 1) q += __shfl_down(q, o);
    __shared__ float red2[4];
    if ((tid & 63) == 0) red2[tid >> 6] = q;
    __syncthreads();
    float var = (red2[0] + red2[1] + red2[2] + red2[3]) * (1.0f / CEMB);
    float rs = rsqrtf(var + 1e-5f);
    bf16* orow = out + (size_t)row * CEMB;
    orow[tid]       = f2bf(d0 * rs * gamma[tid]       + beta[tid]);
    orow[tid + 256] = f2bf(d1 * rs * gamma[tid + 256] + beta[tid + 256]);
    orow[tid + 512] = f2bf(d2 * rs * gamma[tid + 512] + beta[tid + 512]);
}

// ---------------- softmax over rows of S [nrows][NP], valid cols < NSEQ -> P bf16
__global__ __launch_bounds__(256) void softmax_kernel(const float* __restrict__ S,
                                                      bf16* __restrict__ P) {
    int row = blockIdx.x * 4 + (threadIdx.x >> 6);
    int lane = threadIdx.x & 63;
    const float* srow = S + (size_t)row * NP;
    bf16* prow = P + (size_t)row * NP;
    float v[10];
    float mx = -1e30f;
    #pragma unroll
    for (int t = 0; t < 10; t++) {
        int j = lane + t * 64;
        float xv = srow[j];
        bool valid = j < NSEQ;
        v[t] = valid ? xv : -1e30f;
        if (valid) mx = fmaxf(mx, xv);
    }
    #pragma unroll
    for (int o = 32; o > 0; o >>= 1) mx = fmaxf(mx, __shfl_xor(mx, o));
    float sum = 0.f;
    #pragma unroll
    for (int t = 0; t < 10; t++) {
        float e = (v[t] > -1e29f) ? __expf(v[t] - mx) : 0.f;
        v[t] = e; sum += e;
    }
    #pragma unroll
    for (int o = 32; o > 0; o >>= 1) sum += __shfl_xor(sum, o);
    float inv = 1.0f / sum;
    #pragma unroll
    for (int t = 0; t < 10; t++) {
        int j = lane + t * 64;
        prow[j] = f2bf(v[t] * inv);   // pad cols exact 0
    }
}

#define MODE_S    0
#define MODE_QKV  1
#define MODE_PV   2
#define MODE_PROJ 3
#define MODE_FC1  4
#define MODE_FC2  5

struct GemmParams {
    const bf16* A;
    const bf16* Bt;
    int M, N, K;            // padded dims: gemm128 needs M,N %128==0; K%32==0
    int Mreal;              // epilogue row bound
    long sA, sB, sC;        // batch strides (elements)
    float alpha;
    float* Cf;
    bf16* Cb;
    const float* bias;
    const float* resid;
    bf16* qb; bf16* kb; bf16* vtb;
    int headBase;
};

// ---------------- 128x128 tile, BK=32, global_load_lds staging (m97 structure)
template<int MODE>
__global__ __launch_bounds__(256) void gemm128(GemmParams p) {
    __shared__ bf16 As[128 * 32];
    __shared__ bf16 Bs[128 * 32];
    const int tid  = threadIdx.x;
    const int lane = tid & 63;
    const int w    = tid >> 6;
    const int bm = blockIdx.x * 128;
    const int bn = blockIdx.y * 128;
    const int bz = blockIdx.z;
    const bf16* A  = p.A  + (size_t)bz * p.sA;
    const bf16* Bt = p.Bt + (size_t)bz * p.sB;
    const int wr = (w >> 1) * 64;
    const int wc = (w & 1) * 64;
    const int fr = lane & 15;
    const int fk = (lane >> 4) * 8;
    const int idx0 = w * 64 + lane;     // 0..255
    const int idx1 = idx0 + 256;        // 256..511

    const int r0 = idx0 >> 2, c0 = (idx0 & 3) * 8;
    const int r1 = idx1 >> 2, c1 = (idx1 & 3) * 8;

    f32x4 acc[4][4] = {};

    for (int k0 = 0; k0 < p.K; k0 += 32) {
        __syncthreads();
        GLOAD_LDS16(A  + (size_t)(bm + r0) * p.K + k0 + c0, As + (size_t)w * 512);
        GLOAD_LDS16(A  + (size_t)(bm + r1) * p.K + k0 + c1, As + (size_t)(w + 4) * 512);
        GLOAD_LDS16(Bt + (size_t)(bn + r0) * p.K + k0 + c0, Bs + (size_t)w * 512);
        GLOAD_LDS16(Bt + (size_t)(bn + r1) * p.K + k0 + c1, Bs + (size_t)(w + 4) * 512);
        __syncthreads();
        short8 a[4], b[4];
        #pragma unroll
        for (int m = 0; m < 4; m++)
            a[m] = *reinterpret_cast<const short8*>(&As[(wr + m * 16 + fr) * 32 + fk]);
        #pragma unroll
        for (int n = 0; n < 4; n++)
            b[n] = *reinterpret_cast<const short8*>(&Bs[(wc + n * 16 + fr) * 32 + fk]);
        #pragma unroll
        for (int m = 0; m < 4; m++)
            #pragma unroll
            for (int n = 0; n < 4; n++)
                acc[m][n] = __builtin_amdgcn_mfma_f32_16x16x32_bf16(a[m], b[n], acc[m][n], 0, 0, 0);
    }

    const int fq = (lane >> 4) * 4;
    #pragma unroll
    for (int m = 0; m < 4; m++)
    #pragma unroll
    for (int n = 0; n < 4; n++)
    #pragma unroll
    for (int r = 0; r < 4; r++) {
        int row = bm + wr + m * 16 + fq + r;
        int col = bn + wc + n * 16 + fr;
        float val = acc[m][n][r];
        if (MODE == MODE_S) {
            p.Cf[(size_t)bz * p.sC + (size_t)row * p.N + col] = val * p.alpha;
        } else if (MODE == MODE_QKV) {
            if (row < p.Mreal) {
                int b = row / NSEQ; int n2 = row - b * NSEQ;    // chunk-local batch
                int which = col / CEMB; int within = col - which * CEMB;
                int hh = within >> 6; int d = within & 63;
                size_t bh = (size_t)(b * NHEADS + hh);
                bf16 ov = f2bf(val);
                if (which == 0)      p.qb [(bh * NP + n2) * HDIM + d] = ov;
                else if (which == 1) p.kb [(bh * NP + n2) * HDIM + d] = ov;
                else                 p.vtb[(bh * HDIM + d) * NP + n2] = ov;
            }
        } else if (MODE == MODE_PROJ) {
            if (row < p.Mreal) {
                size_t idx = (size_t)row * p.N + col;
                p.Cf[idx] = val + p.bias[col] + p.resid[idx];
            }
        } else if (MODE == MODE_FC1) {
            if (row < p.Mreal) {
                float t = val + p.bias[col];
                float gl = 0.5f * t * (1.0f + erff(t * 0.70710678118f));
                p.Cb[(size_t)row * p.N + col] = f2bf(gl);
            }
        } else if (MODE == MODE_FC2) {
            if (row < p.Mreal) {
                size_t idx = (size_t)row * p.N + col;
                p.Cf[idx] = val + p.bias[col] + p.resid[idx];
            }
        }
    }
}

// ---------------- 64x64 tile fallback (used for PV: N=64)
template<int MODE>
__global__ __launch_bounds__(256) void gemm_bt(GemmParams p) {
    __shared__ bf16 As[64][40];
    __shared__ bf16 Bs[64][40];
    const int tid  = threadIdx.x;
    const int lane = tid & 63;
    const int wave = tid >> 6;
    const int bm = blockIdx.x * 64;
    const int bn = blockIdx.y * 64;
    const int bz = blockIdx.z;
    const bf16* A  = p.A  + (size_t)bz * p.sA;
    const bf16* Bt = p.Bt + (size_t)bz * p.sB;
    const int wr = (wave >> 1) * 32;
    const int wc = (wave & 1) * 32;
    const int lr = tid >> 2;
    const int lk = (tid & 3) * 8;
    const int fr = lane & 15;
    const int fk = (lane >> 4) * 8;

    f32x4 acc[2][2];
    #pragma unroll
    for (int i = 0; i < 2; i++)
        #pragma unroll
        for (int j = 0; j < 2; j++) acc[i][j] = (f32x4){0.f,0.f,0.f,0.f};

    for (int k0 = 0; k0 < p.K; k0 += 32) {
        uint4 av = *reinterpret_cast<const uint4*>(A  + (size_t)(bm + lr) * p.K + k0 + lk);
        uint4 bv = *reinterpret_cast<const uint4*>(Bt + (size_t)(bn + lr) * p.K + k0 + lk);
        __syncthreads();
        *reinterpret_cast<uint4*>(&As[lr][lk]) = av;
        *reinterpret_cast<uint4*>(&Bs[lr][lk]) = bv;
        __syncthreads();
        short8 a0 = *reinterpret_cast<const short8*>(&As[wr + fr][fk]);
        short8 a1 = *reinterpret_cast<const short8*>(&As[wr + 16 + fr][fk]);
        short8 b0 = *reinterpret_cast<const short8*>(&Bs[wc + fr][fk]);
        short8 b1 = *reinterpret_cast<const short8*>(&Bs[wc + 16 + fr][fk]);
        acc[0][0] = __builtin_amdgcn_mfma_f32_16x16x32_bf16(a0, b0, acc[0][0], 0, 0, 0);
        acc[0][1] = __builtin_amdgcn_mfma_f32_16x16x32_bf16(a0, b1, acc[0][1], 0, 0, 0);
        acc[1][0] = __builtin_amdgcn_mfma_f32_16x16x32_bf16(a1, b0, acc[1][0], 0, 0, 0);
        acc[1][1] = __builtin_amdgcn_mfma_f32_16x16x32_bf16(a1, b1, acc[1][1], 0, 0, 0);
    }

    const int fq = (lane >> 4) * 4;
    #pragma unroll
    for (int i = 0; i < 2; i++)
    #pragma unroll
    for (int j = 0; j < 2; j++)
    #pragma unroll
    for (int r = 0; r < 4; r++) {
        int row = bm + wr + i * 16 + fq + r;
        int col = bn + wc + j * 16 + fr;
        float val = acc[i][j][r];
        if (MODE == MODE_PV) {
            if (row < NSEQ) {
                int g = p.headBase + bz; int b = g / NHEADS; int hh = g - b * NHEADS;
                p.Cb[((size_t)(b * NSEQ + row)) * CEMB + hh * HDIM + col] = f2bf(val);
            }
        }
    }
}

extern "C" void kernel_launch(void* const* d_in, const int* in_sizes, int n_in,
                              void* d_out, int out_size, void* d_ws, size_t ws_size,
                              hipStream_t stream) {
    const float* x      = (const float*)d_in[0];
    const float* ln1_g  = (const float*)d_in[1];
    const float* ln1_b  = (const float*)d_in[2];
    const float* w_qkv  = (const float*)d_in[3];
    const float* w_proj = (const float*)d_in[4];
    const float* b_proj = (const float*)d_in[5];
    const float* ln2_g  = (const float*)d_in[6];
    const float* ln2_b  = (const float*)d_in[7];
    const float* w_fc1  = (const float*)d_in[8];
    const float* b_fc1  = (const float*)d_in[9];
    const float* w_fc2  = (const float*)d_in[10];
    const float* b_fc2  = (const float*)d_in[11];
    float* out = (float*)d_out;

    char* ws = (char*)d_ws;
    auto al = [](size_t b){ return (b + 255) & ~(size_t)255; };
    size_t off = 0;
    auto take = [&](size_t b)->char* { char* p = ws + off; off += al(b); return p; };

    // ---- fixed allocations (always live) ----
    bf16* wqkvT  = (bf16*)take((size_t)2304 * 768 * 2);
    bf16* wprojT = (bf16*)take((size_t)768 * 768 * 2);
    bf16* wfc1T  = (bf16*)take((size_t)3072 * 768 * 2);
    bf16* wfc2T  = (bf16*)take((size_t)768 * 3072 * 2);
    bf16* h      = (bf16*)take((size_t)(NTOK + 128) * CEMB * 2);  // +128 pad rows
    bf16* o      = (bf16*)take((size_t)(NTOK + 128) * CEMB * 2);  // +128 pad rows
    size_t fixedEnd = off;

    // ---- choose batch-chunk size CB so scratch region fits ws_size ----
    int CB = 16;
    int heads = 0, nMlp = 0, mlpRows = 0, mlpPad = 0;
    size_t qkvB = 0, SB = 0, PB = 0;
    while (true) {
        heads  = CB * NHEADS;
        qkvB   = al((size_t)heads * NP * HDIM * 2);
        SB     = al((size_t)heads * NP * NP * 4);
        PB     = al((size_t)heads * NP * NP * 2);
        nMlp   = 16 / CB;
        mlpRows = NTOK / nMlp;
        mlpPad  = (mlpRows + 127) & ~127;
        size_t gB = al((size_t)mlpPad * CHID * 2);
        size_t attn = 3 * qkvB + SB + PB;
        size_t region = attn > gB ? attn : gB;
        if (fixedEnd + region <= ws_size || CB == 1) break;
        CB >>= 1;
    }
    bf16*  q_c  = (bf16*)(ws + fixedEnd);
    bf16*  k_c  = (bf16*)(ws + fixedEnd + qkvB);
    bf16*  vT_c = (bf16*)(ws + fixedEnd + 2 * qkvB);
    float* S    = (float*)(ws + fixedEnd + 3 * qkvB);
    bf16*  P    = (bf16*)(ws + fixedEnd + 3 * qkvB + SB);
    bf16*  g_c  = (bf16*)(ws + fixedEnd);   // MLP phase reuses the region

    // ---- weights -> bf16 transposed ----
    transpose_w<<<(768 * 2304 + 255) / 256, 256, 0, stream>>>(w_qkv, wqkvT, 768, 2304);
    transpose_w<<<(768 * 768 + 255) / 256, 256, 0, stream>>>(w_proj, wprojT, 768, 768);
    transpose_w<<<(768 * 3072 + 255) / 256, 256, 0, stream>>>(w_fc1, wfc1T, 768, 3072);
    transpose_w<<<(3072 * 768 + 255) / 256, 256, 0, stream>>>(w_fc2, wfc2T, 3072, 768);

    // ---- LN1: x -> h (bf16) ----
    ln_kernel<<<NTOK, 256, 0, stream>>>(x, ln1_g, ln1_b, h);

    // ---- attention, chunks of CB batches ----
    const int qRows = CB * NSEQ;
    const int qPad  = (qRows + 127) & ~127;
    for (int c = 0; c < NBATCH / CB; c++) {
        {   // QKV GEMM for this chunk, scatter epilogue into q_c/k_c/vT_c
            GemmParams p{};
            p.A = h + (size_t)(c * qRows) * CEMB; p.Bt = wqkvT;
            p.M = qPad; p.N = 3 * CEMB; p.K = CEMB; p.Mreal = qRows;
            p.qb = q_c; p.kb = k_c; p.vtb = vT_c;
            gemm128<MODE_QKV><<<dim3(qPad / 128, 3 * CEMB / 128, 1), 256, 0, stream>>>(p);
        }
        {   // S = Q K^T * scale
            GemmParams p{};
            p.A = q_c; p.Bt = k_c;
            p.M = NP; p.N = NP; p.K = HDIM; p.Mreal = NP;
            p.sA = (long)NP * HDIM; p.sB = (long)NP * HDIM; p.sC = (long)NP * NP;
            p.alpha = 0.125f; p.Cf = S;
            gemm128<MODE_S><<<dim3(NP / 128, NP / 128, heads), 256, 0, stream>>>(p);
        }
        softmax_kernel<<<heads * NP / 4, 256, 0, stream>>>(S, P);
        {   // O = P V  (vT_c is V^T per head)
            GemmParams p{};
            p.A = P; p.Bt = vT_c;
            p.M = NP; p.N = HDIM; p.K = NP; p.Mreal = NP;
            p.sA = (long)NP * NP; p.sB = (long)HDIM * NP; p.sC = 0;
            p.Cb = o; p.headBase = c * heads;
            gemm_bt<MODE_PV><<<dim3(NP / 64, HDIM / 64, heads), 256, 0, stream>>>(p);
        }
    }

    // ---- proj + bias + residual -> out (fp32, acts as x1) ----
    {
        GemmParams p{};
        p.A = o; p.Bt = wprojT;
        p.M = (NTOK + 127) & ~127; p.N = CEMB; p.K = CEMB; p.Mreal = NTOK;
        p.Cf = out; p.bias = b_proj; p.resid = x;
        gemm128<MODE_PROJ><<<dim3(((NTOK + 127) & ~127) / 128, CEMB / 128, 1), 256, 0, stream>>>(p);
    }

    // ---- LN2: out -> h (bf16) ----
    ln_kernel<<<NTOK, 256, 0, stream>>>(out, ln2_g, ln2_b, h);

    // ---- MLP, chunked over rows ----
    for (int j = 0; j < nMlp; j++) {
        const size_t r0 = (size_t)j * mlpRows;
        {   // FC1 + GELU -> g_c (bf16)
            GemmParams p{};
            p.A = h + r0 * CEMB; p.Bt = wfc1T;
            p.M = mlpPad; p.N = CHID; p.K = CEMB; p.Mreal = mlpRows;
            p.Cb = g_c; p.bias = b_fc1;
            gemm128<MODE_FC1><<<dim3(mlpPad / 128, CHID / 128, 1), 256, 0, stream>>>(p);
        }
        {   // FC2 + bias + residual (in-place on out)
            GemmParams p{};
            p.A = g_c; p.Bt = wfc2T;
            p.M = mlpPad; p.N = CEMB; p.K = CHID; p.Mreal = mlpRows;
            p.Cf = out + r0 * CEMB; p.bias = b_fc2; p.resid = out + r0 * CEMB;
            gemm128<MODE_FC2><<<dim3(mlpPad / 128, CEMB / 128, 1), 256, 0, stream>>>(p);
        }
    }
}

// Round 4
// 1767.957 us; speedup vs baseline: 1.4987x; 1.3180x over previous
//
#include <hip/hip_runtime.h>
#include <hip/hip_bf16.h>
#include <math.h>

using bf16 = __hip_bfloat16;
typedef __attribute__((ext_vector_type(8))) short short8;
typedef __attribute__((ext_vector_type(4))) float f32x4;

#define NSEQ   577
#define NBATCH 64
#define NTOK   36928   // 64*577
#define NHEADS 12
#define HDIM   64
#define NP     640     // padded seq len (multiple of 128)
#define CEMB   768
#define CHID   3072
#define NBH    (NBATCH*NHEADS)   // 768 head instances

__device__ __forceinline__ bf16 f2bf(float v){ return __float2bfloat16(v); }

#define GLOAD_LDS16(gaddr, laddr) \
  __builtin_amdgcn_global_load_lds((__attribute__((address_space(1))) const void*)(gaddr), \
                                   (__attribute__((address_space(3))) void*)(laddr), 16, 0, 0)

// ---------------- weight convert+transpose: src fp32 [R][C] -> dst bf16 [C][R]
__global__ __launch_bounds__(256) void transpose_w(const float* __restrict__ src,
                                                   bf16* __restrict__ dst, int R, int C) {
    long idx = (long)blockIdx.x * 256 + threadIdx.x;
    long total = (long)R * C;
    if (idx < total) {
        int r = (int)(idx / C);
        int c = (int)(idx - (long)r * C);
        dst[(long)c * R + r] = f2bf(src[idx]);
    }
}

// ---------------- LayerNorm: fp32 [rows][768] -> bf16 [rows][768]
__global__ __launch_bounds__(256) void ln_kernel(const float* __restrict__ x,
                                                 const float* __restrict__ gamma,
                                                 const float* __restrict__ beta,
                                                 bf16* __restrict__ out) {
    int row = blockIdx.x;
    const float* xr = x + (size_t)row * CEMB;
    int tid = threadIdx.x;
    float v0 = xr[tid], v1 = xr[tid + 256], v2 = xr[tid + 512];
    float s = v0 + v1 + v2;
    #pragma unroll
    for (int o = 32; o > 0; o >>= 1) s += __shfl_down(s, o);
    __shared__ float red[4];
    if ((tid & 63) == 0) red[tid >> 6] = s;
    __syncthreads();
    float mean = (red[0] + red[1] + red[2] + red[3]) * (1.0f / CEMB);
    float d0 = v0 - mean, d1 = v1 - mean, d2 = v2 - mean;
    float q = d0*d0 + d1*d1 + d2*d2;
    #pragma unroll
    for (int o = 32; o > 0; o >>= 1) q += __shfl_down(q, o);
    __shared__ float red2[4];
    if ((tid & 63) == 0) red2[tid >> 6] = q;
    __syncthreads();
    float var = (red2[0] + red2[1] + red2[2] + red2[3]) * (1.0f / CEMB);
    float rs = rsqrtf(var + 1e-5f);
    bf16* orow = out + (size_t)row * CEMB;
    orow[tid]       = f2bf(d0 * rs * gamma[tid]       + beta[tid]);
    orow[tid + 256] = f2bf(d1 * rs * gamma[tid + 256] + beta[tid + 256]);
    orow[tid + 512] = f2bf(d2 * rs * gamma[tid + 512] + beta[tid + 512]);
}

// ---------------- fused flash attention ----------------
// q,k: [bh][NP][64] bf16 ; vT: [bh][64][NP] bf16 (pads zeroed)
// out o: [b*NSEQ + row][CEMB] at col h*64, bf16
__global__ __launch_bounds__(256) void flash_attn(const bf16* __restrict__ qg,
                                                  const bf16* __restrict__ kg,
                                                  const bf16* __restrict__ vtg,
                                                  bf16* __restrict__ og) {
    const int tid = threadIdx.x, lane = tid & 63, w = tid >> 6;
    const int fr = lane & 15, fh = lane >> 4;
    const int bh = blockIdx.y;
    const int q0 = blockIdx.x * 128;
    const int wr = w * 32;

    __shared__ bf16 Ks[64 * 64];    // [key][d]
    __shared__ bf16 Vs[64 * 64];    // [d][key]
    __shared__ bf16 Ps[128 * 64];   // [qrow][key]

    const bf16* qb = qg  + (size_t)bh * NP * HDIM;
    const bf16* kb = kg  + (size_t)bh * NP * HDIM;
    const bf16* vb = vtg + (size_t)bh * HDIM * NP;

    // Q fragments in registers (A-operand: row = fr, k = fh*8..)
    short8 qa[2][2];
    #pragma unroll
    for (int mi = 0; mi < 2; mi++)
        #pragma unroll
        for (int ks = 0; ks < 2; ks++)
            qa[mi][ks] = *reinterpret_cast<const short8*>(
                qb + (size_t)(q0 + wr + mi * 16 + fr) * HDIM + ks * 32 + fh * 8);

    f32x4 od[2][4] = {};
    float m_run[2][4], l_run[2][4];
    #pragma unroll
    for (int mi = 0; mi < 2; mi++)
        #pragma unroll
        for (int r = 0; r < 4; r++) { m_run[mi][r] = -1e30f; l_run[mi][r] = 0.f; }

    for (int t = 0; t < NP / 64; t++) {
        const int kb0 = t * 64;
        __syncthreads();
        // stage K tile (contiguous 8KB)
        {
            const bf16* src = kb + (size_t)kb0 * HDIM;
            GLOAD_LDS16(src + w * 512 + lane * 8,        Ks + w * 512);
            GLOAD_LDS16(src + 2048 + w * 512 + lane * 8, Ks + 2048 + w * 512);
        }
        // stage V^T tile: Vs[d][key], rows strided NP in global
        {
            int d0 = w * 8;
            GLOAD_LDS16(vb + (size_t)(d0 + (lane >> 3)) * NP + kb0 + (lane & 7) * 8,
                        Vs + d0 * 64);
            d0 = 32 + w * 8;
            GLOAD_LDS16(vb + (size_t)(d0 + (lane >> 3)) * NP + kb0 + (lane & 7) * 8,
                        Vs + d0 * 64);
        }
        __syncthreads();

        // S = Q K^T
        f32x4 sacc[2][4] = {};
        short8 kf[4][2];
        #pragma unroll
        for (int n = 0; n < 4; n++)
            #pragma unroll
            for (int ks = 0; ks < 2; ks++)
                kf[n][ks] = *reinterpret_cast<const short8*>(&Ks[(n * 16 + fr) * 64 + ks * 32 + fh * 8]);
        #pragma unroll
        for (int mi = 0; mi < 2; mi++)
            #pragma unroll
            for (int n = 0; n < 4; n++)
                #pragma unroll
                for (int ks = 0; ks < 2; ks++)
                    sacc[mi][n] = __builtin_amdgcn_mfma_f32_16x16x32_bf16(qa[mi][ks], kf[n][ks], sacc[mi][n], 0, 0, 0);

        // online softmax (row = wr+mi*16+fh*4+r, each value replicated over fr-lanes)
        #pragma unroll
        for (int mi = 0; mi < 2; mi++) {
            float sv[4][4];
            float tm[4] = {-1e30f, -1e30f, -1e30f, -1e30f};
            #pragma unroll
            for (int n = 0; n < 4; n++) {
                int col = kb0 + n * 16 + fr;
                bool valid = col < NSEQ;
                #pragma unroll
                for (int r = 0; r < 4; r++) {
                    float s = sacc[mi][n][r] * 0.125f;
                    sv[n][r] = valid ? s : -1e30f;
                    tm[r] = fmaxf(tm[r], sv[n][r]);
                }
            }
            #pragma unroll
            for (int r = 0; r < 4; r++) {
                #pragma unroll
                for (int o = 1; o < 16; o <<= 1) tm[r] = fmaxf(tm[r], __shfl_xor(tm[r], o));
                float mn = fmaxf(m_run[mi][r], tm[r]);
                float sc = __expf(m_run[mi][r] - mn);
                m_run[mi][r] = mn;
                float ps = 0.f;
                #pragma unroll
                for (int n = 0; n < 4; n++) {
                    float e = __expf(sv[n][r] - mn);
                    sv[n][r] = e; ps += e;
                }
                #pragma unroll
                for (int o = 1; o < 16; o <<= 1) ps += __shfl_xor(ps, o);
                l_run[mi][r] = l_run[mi][r] * sc + ps;
                #pragma unroll
                for (int n2 = 0; n2 < 4; n2++) od[mi][n2][r] *= sc;
            }
            #pragma unroll
            for (int n = 0; n < 4; n++)
                #pragma unroll
                for (int r = 0; r < 4; r++)
                    Ps[(wr + mi * 16 + fh * 4 + r) * 64 + n * 16 + fr] = f2bf(sv[n][r]);
        }
        __syncthreads();

        // O += P V  (A = Ps rows=qrow; B = Vs rows=d)
        short8 pa[2][2], vf[4][2];
        #pragma unroll
        for (int mi = 0; mi < 2; mi++)
            #pragma unroll
            for (int ks = 0; ks < 2; ks++)
                pa[mi][ks] = *reinterpret_cast<const short8*>(&Ps[(wr + mi * 16 + fr) * 64 + ks * 32 + fh * 8]);
        #pragma unroll
        for (int n2 = 0; n2 < 4; n2++)
            #pragma unroll
            for (int ks = 0; ks < 2; ks++)
                vf[n2][ks] = *reinterpret_cast<const short8*>(&Vs[(n2 * 16 + fr) * 64 + ks * 32 + fh * 8]);
        #pragma unroll
        for (int mi = 0; mi < 2; mi++)
            #pragma unroll
            for (int n2 = 0; n2 < 4; n2++)
                #pragma unroll
                for (int ks = 0; ks < 2; ks++)
                    od[mi][n2] = __builtin_amdgcn_mfma_f32_16x16x32_bf16(pa[mi][ks], vf[n2][ks], od[mi][n2], 0, 0, 0);
    }

    // epilogue
    const int b = bh / NHEADS, hh = bh - b * NHEADS;
    #pragma unroll
    for (int mi = 0; mi < 2; mi++)
        #pragma unroll
        for (int r = 0; r < 4; r++) {
            int qrow = q0 + wr + mi * 16 + fh * 4 + r;
            if (qrow < NSEQ) {
                float inv = 1.f / l_run[mi][r];
                #pragma unroll
                for (int n2 = 0; n2 < 4; n2++)
                    og[((size_t)(b * NSEQ + qrow)) * CEMB + hh * HDIM + n2 * 16 + fr] =
                        f2bf(od[mi][n2][r] * inv);
            }
        }
}

// ---------------- generic 128x128 MFMA GEMM with epilogues
#define MODE_QKV  1
#define MODE_PROJ 3
#define MODE_FC1  4
#define MODE_FC2  5

struct GemmParams {
    const bf16* A;
    const bf16* Bt;
    int M, N, K;            // M,N %128==0; K%32==0
    int Mreal;
    float* Cf;
    bf16* Cb;
    const float* bias;
    const float* resid;
    bf16* qb; bf16* kb; bf16* vtb;
};

template<int MODE>
__global__ __launch_bounds__(256) void gemm128(GemmParams p) {
    __shared__ bf16 As[128 * 32];
    __shared__ bf16 Bs[128 * 32];
    const int tid  = threadIdx.x;
    const int lane = tid & 63;
    const int w    = tid >> 6;

    // bijective XCD swizzle (m204): each XCD gets a contiguous tile range
    const int nwg = gridDim.x * gridDim.y;
    const int lin = blockIdx.y * gridDim.x + blockIdx.x;
    const int q8 = nwg >> 3, r8 = nwg & 7;
    const int xcd = lin & 7, idx = lin >> 3;
    const int lin2 = ((xcd < r8) ? xcd * (q8 + 1) : r8 * (q8 + 1) + (xcd - r8) * q8) + idx;
    const int bm = (lin2 % gridDim.x) * 128;
    const int bn = (lin2 / gridDim.x) * 128;

    const bf16* A  = p.A;
    const bf16* Bt = p.Bt;
    const int wr = (w >> 1) * 64;
    const int wc = (w & 1) * 64;
    const int fr = lane & 15;
    const int fk = (lane >> 4) * 8;
    const int idx0 = w * 64 + lane;
    const int idx1 = idx0 + 256;
    const int r0 = idx0 >> 2, c0 = (idx0 & 3) * 8;
    const int r1 = idx1 >> 2, c1 = (idx1 & 3) * 8;

    f32x4 acc[4][4] = {};

    for (int k0 = 0; k0 < p.K; k0 += 32) {
        __syncthreads();
        GLOAD_LDS16(A  + (size_t)(bm + r0) * p.K + k0 + c0, As + (size_t)w * 512);
        GLOAD_LDS16(A  + (size_t)(bm + r1) * p.K + k0 + c1, As + (size_t)(w + 4) * 512);
        GLOAD_LDS16(Bt + (size_t)(bn + r0) * p.K + k0 + c0, Bs + (size_t)w * 512);
        GLOAD_LDS16(Bt + (size_t)(bn + r1) * p.K + k0 + c1, Bs + (size_t)(w + 4) * 512);
        __syncthreads();
        short8 a[4], b[4];
        #pragma unroll
        for (int m = 0; m < 4; m++)
            a[m] = *reinterpret_cast<const short8*>(&As[(wr + m * 16 + fr) * 32 + fk]);
        #pragma unroll
        for (int n = 0; n < 4; n++)
            b[n] = *reinterpret_cast<const short8*>(&Bs[(wc + n * 16 + fr) * 32 + fk]);
        #pragma unroll
        for (int m = 0; m < 4; m++)
            #pragma unroll
            for (int n = 0; n < 4; n++)
                acc[m][n] = __builtin_amdgcn_mfma_f32_16x16x32_bf16(a[m], b[n], acc[m][n], 0, 0, 0);
    }

    const int fq = (lane >> 4) * 4;
    #pragma unroll
    for (int m = 0; m < 4; m++)
    #pragma unroll
    for (int n = 0; n < 4; n++)
    #pragma unroll
    for (int r = 0; r < 4; r++) {
        int row = bm + wr + m * 16 + fq + r;
        int col = bn + wc + n * 16 + fr;
        float val = acc[m][n][r];
        if (MODE == MODE_QKV) {
            if (row < p.Mreal) {
                int b2 = row / NSEQ; int n2 = row - b2 * NSEQ;
                int which = col / CEMB; int within = col - which * CEMB;
                int hh = within >> 6; int d = within & 63;
                size_t bh = (size_t)(b2 * NHEADS + hh);
                bf16 ov = f2bf(val);
                if (which == 0)      p.qb [(bh * NP + n2) * HDIM + d] = ov;
                else if (which == 1) p.kb [(bh * NP + n2) * HDIM + d] = ov;
                else                 p.vtb[(bh * HDIM + d) * NP + n2] = ov;
            }
        } else if (MODE == MODE_PROJ) {
            if (row < p.Mreal) {
                size_t idx2 = (size_t)row * p.N + col;
                p.Cf[idx2] = val + p.bias[col] + p.resid[idx2];
            }
        } else if (MODE == MODE_FC1) {
            if (row < p.Mreal) {
                float t = val + p.bias[col];
                float gl = 0.5f * t * (1.0f + erff(t * 0.70710678118f));
                p.Cb[(size_t)row * p.N + col] = f2bf(gl);
            }
        } else if (MODE == MODE_FC2) {
            if (row < p.Mreal) {
                size_t idx2 = (size_t)row * p.N + col;
                p.Cf[idx2] = val + p.bias[col] + p.resid[idx2];
            }
        }
    }
}

extern "C" void kernel_launch(void* const* d_in, const int* in_sizes, int n_in,
                              void* d_out, int out_size, void* d_ws, size_t ws_size,
                              hipStream_t stream) {
    const float* x      = (const float*)d_in[0];
    const float* ln1_g  = (const float*)d_in[1];
    const float* ln1_b  = (const float*)d_in[2];
    const float* w_qkv  = (const float*)d_in[3];
    const float* w_proj = (const float*)d_in[4];
    const float* b_proj = (const float*)d_in[5];
    const float* ln2_g  = (const float*)d_in[6];
    const float* ln2_b  = (const float*)d_in[7];
    const float* w_fc1  = (const float*)d_in[8];
    const float* b_fc1  = (const float*)d_in[9];
    const float* w_fc2  = (const float*)d_in[10];
    const float* b_fc2  = (const float*)d_in[11];
    float* out = (float*)d_out;

    char* ws = (char*)d_ws;
    auto al = [](size_t b){ return (b + 255) & ~(size_t)255; };
    size_t off = 0;
    auto take = [&](size_t b)->char* { char* p = ws + off; off += al(b); return p; };

    // ---- fixed allocations ----
    bf16* wqkvT  = (bf16*)take((size_t)2304 * 768 * 2);
    bf16* wprojT = (bf16*)take((size_t)768 * 768 * 2);
    bf16* wfc1T  = (bf16*)take((size_t)3072 * 768 * 2);
    bf16* wfc2T  = (bf16*)take((size_t)768 * 3072 * 2);
    bf16* h      = (bf16*)take((size_t)(NTOK + 128) * CEMB * 2);
    bf16* o      = (bf16*)take((size_t)(NTOK + 128) * CEMB * 2);
    size_t fixedEnd = off;

    // ---- overlay region: attention q/k/vT  OR  MLP hidden g ----
    const size_t qkvB = (size_t)NBH * NP * HDIM * 2;      // 62,914,560 B each
    bf16* q_c  = (bf16*)(ws + fixedEnd);
    bf16* k_c  = (bf16*)(ws + fixedEnd + qkvB);
    bf16* vT_c = (bf16*)(ws + fixedEnd + 2 * qkvB);
    bf16* g_c  = (bf16*)(ws + fixedEnd);                  // MLP reuses region

    // ---- weights -> bf16 transposed ----
    transpose_w<<<(768 * 2304 + 255) / 256, 256, 0, stream>>>(w_qkv, wqkvT, 768, 2304);
    transpose_w<<<(768 * 768 + 255) / 256, 256, 0, stream>>>(w_proj, wprojT, 768, 768);
    transpose_w<<<(768 * 3072 + 255) / 256, 256, 0, stream>>>(w_fc1, wfc1T, 768, 3072);
    transpose_w<<<(3072 * 768 + 255) / 256, 256, 0, stream>>>(w_fc2, wfc2T, 3072, 768);

    // zero q/k/vT (pad rows/cols must be finite-zero for flash)
    hipMemsetAsync(q_c, 0, 3 * qkvB, stream);

    // ---- LN1: x -> h ----
    ln_kernel<<<NTOK, 256, 0, stream>>>(x, ln1_g, ln1_b, h);

    // ---- QKV GEMM (single launch) ----
    {
        const int mPad = (NTOK + 127) & ~127;   // 36992
        GemmParams p{};
        p.A = h; p.Bt = wqkvT;
        p.M = mPad; p.N = 3 * CEMB; p.K = CEMB; p.Mreal = NTOK;
        p.qb = q_c; p.kb = k_c; p.vtb = vT_c;
        gemm128<MODE_QKV><<<dim3(mPad / 128, 3 * CEMB / 128), 256, 0, stream>>>(p);
    }

    // ---- fused flash attention -> o ----
    flash_attn<<<dim3(NP / 128, NBH), 256, 0, stream>>>(q_c, k_c, vT_c, o);

    // ---- proj + bias + residual -> out ----
    {
        const int mPad = (NTOK + 127) & ~127;
        GemmParams p{};
        p.A = o; p.Bt = wprojT;
        p.M = mPad; p.N = CEMB; p.K = CEMB; p.Mreal = NTOK;
        p.Cf = out; p.bias = b_proj; p.resid = x;
        gemm128<MODE_PROJ><<<dim3(mPad / 128, CEMB / 128), 256, 0, stream>>>(p);
    }

    // ---- LN2: out -> h ----
    ln_kernel<<<NTOK, 256, 0, stream>>>(out, ln2_g, ln2_b, h);

    // ---- FC1 + GELU -> g_c ----
    {
        const int mPad = (NTOK + 127) & ~127;
        GemmParams p{};
        p.A = h; p.Bt = wfc1T;
        p.M = mPad; p.N = CHID; p.K = CEMB; p.Mreal = NTOK;
        p.Cb = g_c; p.bias = b_fc1;
        gemm128<MODE_FC1><<<dim3(mPad / 128, CHID / 128), 256, 0, stream>>>(p);
    }

    // ---- FC2 + bias + residual (in-place on out) ----
    {
        const int mPad = (NTOK + 127) & ~127;
        GemmParams p{};
        p.A = g_c; p.Bt = wfc2T;
        p.M = mPad; p.N = CEMB; p.K = CHID; p.Mreal = NTOK;
        p.Cf = out; p.bias = b_fc2; p.resid = out;
        gemm128<MODE_FC2><<<dim3(mPad / 128, CEMB / 128), 256, 0, stream>>>(p);
    }
}

// Round 5
// 1596.756 us; speedup vs baseline: 1.6594x; 1.1072x over previous
//
#include <hip/hip_runtime.h>
#include <hip/hip_bf16.h>
#include <math.h>

using bf16 = __hip_bfloat16;
typedef __attribute__((ext_vector_type(8))) short short8;
typedef __attribute__((ext_vector_type(4))) float f32x4;

#define NSEQ   577
#define NBATCH 64
#define NTOK   36928   // 64*577
#define NHEADS 12
#define HDIM   64
#define NP     640     // padded seq len (multiple of 128)
#define CEMB   768
#define CHID   3072
#define NBH    (NBATCH*NHEADS)   // 768 head instances

__device__ __forceinline__ bf16 f2bf(float v){ return __float2bfloat16(v); }

// tanh-form GELU: 0.5x(1+tanh(sqrt(2/pi)(x+0.044715x^3))), tanh via one __expf.
// |err| vs exact-erf gelu ~1e-3 absolute; bf16 storage rounding dominates.
__device__ __forceinline__ float gelu_f(float x) {
    float x3 = x * x * x;
    float y = 1.5957691216057308f * (x + 0.044715f * x3);  // 2*sqrt(2/pi)*(...)
    float e = __expf(y);
    float t = 1.0f - 2.0f / (e + 1.0f);                    // tanh
    return 0.5f * x * (1.0f + t);
}

#define GLOAD_LDS16(gaddr, laddr) \
  __builtin_amdgcn_global_load_lds((__attribute__((address_space(1))) const void*)(gaddr), \
                                   (__attribute__((address_space(3))) void*)(laddr), 16, 0, 0)

// ---------------- weight convert+transpose: src fp32 [R][C] -> dst bf16 [C][R]
__global__ __launch_bounds__(256) void transpose_w(const float* __restrict__ src,
                                                   bf16* __restrict__ dst, int R, int C) {
    long idx = (long)blockIdx.x * 256 + threadIdx.x;
    long total = (long)R * C;
    if (idx < total) {
        int r = (int)(idx / C);
        int c = (int)(idx - (long)r * C);
        dst[(long)c * R + r] = f2bf(src[idx]);
    }
}

// ---------------- LayerNorm: fp32 [rows][768] -> bf16 [rows][768]
__global__ __launch_bounds__(256) void ln_kernel(const float* __restrict__ x,
                                                 const float* __restrict__ gamma,
                                                 const float* __restrict__ beta,
                                                 bf16* __restrict__ out) {
    int row = blockIdx.x;
    const float* xr = x + (size_t)row * CEMB;
    int tid = threadIdx.x;
    float v0 = xr[tid], v1 = xr[tid + 256], v2 = xr[tid + 512];
    float s = v0 + v1 + v2;
    #pragma unroll
    for (int o = 32; o > 0; o >>= 1) s += __shfl_down(s, o);
    __shared__ float red[4];
    if ((tid & 63) == 0) red[tid >> 6] = s;
    __syncthreads();
    float mean = (red[0] + red[1] + red[2] + red[3]) * (1.0f / CEMB);
    float d0 = v0 - mean, d1 = v1 - mean, d2 = v2 - mean;
    float q = d0*d0 + d1*d1 + d2*d2;
    #pragma unroll
    for (int o = 32; o > 0; o >>= 1) q += __shfl_down(q, o);
    __shared__ float red2[4];
    if ((tid & 63) == 0) red2[tid >> 6] = q;
    __syncthreads();
    float var = (red2[0] + red2[1] + red2[2] + red2[3]) * (1.0f / CEMB);
    float rs = rsqrtf(var + 1e-5f);
    bf16* orow = out + (size_t)row * CEMB;
    orow[tid]       = f2bf(d0 * rs * gamma[tid]       + beta[tid]);
    orow[tid + 256] = f2bf(d1 * rs * gamma[tid + 256] + beta[tid + 256]);
    orow[tid + 512] = f2bf(d2 * rs * gamma[tid + 512] + beta[tid + 512]);
}

// ---------------- fused flash attention ----------------
// q,k: [bh][NP][64] bf16 ; vT: [bh][64][NP] bf16
// pads (rows/cols >= NSEQ) may hold arbitrary FINITE garbage: masked before exp.
__global__ __launch_bounds__(256) void flash_attn(const bf16* __restrict__ qg,
                                                  const bf16* __restrict__ kg,
                                                  const bf16* __restrict__ vtg,
                                                  bf16* __restrict__ og) {
    const int tid = threadIdx.x, lane = tid & 63, w = tid >> 6;
    const int fr = lane & 15, fh = lane >> 4;
    const int bh = blockIdx.y;
    const int q0 = blockIdx.x * 128;
    const int wr = w * 32;

    __shared__ bf16 Ks[64 * 64];    // [key][d]
    __shared__ bf16 Vs[64 * 64];    // [d][key]
    __shared__ bf16 Ps[128 * 64];   // [qrow][key]

    const bf16* qb = qg  + (size_t)bh * NP * HDIM;
    const bf16* kb = kg  + (size_t)bh * NP * HDIM;
    const bf16* vb = vtg + (size_t)bh * HDIM * NP;

    short8 qa[2][2];
    #pragma unroll
    for (int mi = 0; mi < 2; mi++)
        #pragma unroll
        for (int ks = 0; ks < 2; ks++)
            qa[mi][ks] = *reinterpret_cast<const short8*>(
                qb + (size_t)(q0 + wr + mi * 16 + fr) * HDIM + ks * 32 + fh * 8);

    f32x4 od[2][4] = {};
    float m_run[2][4], l_run[2][4];
    #pragma unroll
    for (int mi = 0; mi < 2; mi++)
        #pragma unroll
        for (int r = 0; r < 4; r++) { m_run[mi][r] = -1e30f; l_run[mi][r] = 0.f; }

    for (int t = 0; t < NP / 64; t++) {
        const int kb0 = t * 64;
        __syncthreads();
        {
            const bf16* src = kb + (size_t)kb0 * HDIM;
            GLOAD_LDS16(src + w * 512 + lane * 8,        Ks + w * 512);
            GLOAD_LDS16(src + 2048 + w * 512 + lane * 8, Ks + 2048 + w * 512);
        }
        {
            int d0 = w * 8;
            GLOAD_LDS16(vb + (size_t)(d0 + (lane >> 3)) * NP + kb0 + (lane & 7) * 8,
                        Vs + d0 * 64);
            d0 = 32 + w * 8;
            GLOAD_LDS16(vb + (size_t)(d0 + (lane >> 3)) * NP + kb0 + (lane & 7) * 8,
                        Vs + d0 * 64);
        }
        __syncthreads();

        f32x4 sacc[2][4] = {};
        short8 kf[4][2];
        #pragma unroll
        for (int n = 0; n < 4; n++)
            #pragma unroll
            for (int ks = 0; ks < 2; ks++)
                kf[n][ks] = *reinterpret_cast<const short8*>(&Ks[(n * 16 + fr) * 64 + ks * 32 + fh * 8]);
        #pragma unroll
        for (int mi = 0; mi < 2; mi++)
            #pragma unroll
            for (int n = 0; n < 4; n++)
                #pragma unroll
                for (int ks = 0; ks < 2; ks++)
                    sacc[mi][n] = __builtin_amdgcn_mfma_f32_16x16x32_bf16(qa[mi][ks], kf[n][ks], sacc[mi][n], 0, 0, 0);

        #pragma unroll
        for (int mi = 0; mi < 2; mi++) {
            float sv[4][4];
            float tm[4] = {-1e30f, -1e30f, -1e30f, -1e30f};
            #pragma unroll
            for (int n = 0; n < 4; n++) {
                int col = kb0 + n * 16 + fr;
                bool valid = col < NSEQ;
                #pragma unroll
                for (int r = 0; r < 4; r++) {
                    float s = sacc[mi][n][r] * 0.125f;
                    sv[n][r] = valid ? s : -1e30f;
                    tm[r] = fmaxf(tm[r], sv[n][r]);
                }
            }
            #pragma unroll
            for (int r = 0; r < 4; r++) {
                #pragma unroll
                for (int o = 1; o < 16; o <<= 1) tm[r] = fmaxf(tm[r], __shfl_xor(tm[r], o));
                float mn = fmaxf(m_run[mi][r], tm[r]);
                float sc = __expf(m_run[mi][r] - mn);
                m_run[mi][r] = mn;
                float ps = 0.f;
                #pragma unroll
                for (int n = 0; n < 4; n++) {
                    float e = __expf(sv[n][r] - mn);
                    sv[n][r] = e; ps += e;
                }
                #pragma unroll
                for (int o = 1; o < 16; o <<= 1) ps += __shfl_xor(ps, o);
                l_run[mi][r] = l_run[mi][r] * sc + ps;
                #pragma unroll
                for (int n2 = 0; n2 < 4; n2++) od[mi][n2][r] *= sc;
            }
            #pragma unroll
            for (int n = 0; n < 4; n++)
                #pragma unroll
                for (int r = 0; r < 4; r++)
                    Ps[(wr + mi * 16 + fh * 4 + r) * 64 + n * 16 + fr] = f2bf(sv[n][r]);
        }
        __syncthreads();

        short8 pa[2][2], vf[4][2];
        #pragma unroll
        for (int mi = 0; mi < 2; mi++)
            #pragma unroll
            for (int ks = 0; ks < 2; ks++)
                pa[mi][ks] = *reinterpret_cast<const short8*>(&Ps[(wr + mi * 16 + fr) * 64 + ks * 32 + fh * 8]);
        #pragma unroll
        for (int n2 = 0; n2 < 4; n2++)
            #pragma unroll
            for (int ks = 0; ks < 2; ks++)
                vf[n2][ks] = *reinterpret_cast<const short8*>(&Vs[(n2 * 16 + fr) * 64 + ks * 32 + fh * 8]);
        #pragma unroll
        for (int mi = 0; mi < 2; mi++)
            #pragma unroll
            for (int n2 = 0; n2 < 4; n2++)
                #pragma unroll
                for (int ks = 0; ks < 2; ks++)
                    od[mi][n2] = __builtin_amdgcn_mfma_f32_16x16x32_bf16(pa[mi][ks], vf[n2][ks], od[mi][n2], 0, 0, 0);
    }

    const int b = bh / NHEADS, hh = bh - b * NHEADS;
    #pragma unroll
    for (int mi = 0; mi < 2; mi++)
        #pragma unroll
        for (int r = 0; r < 4; r++) {
            int qrow = q0 + wr + mi * 16 + fh * 4 + r;
            if (qrow < NSEQ) {
                float inv = 1.f / l_run[mi][r];
                #pragma unroll
                for (int n2 = 0; n2 < 4; n2++)
                    og[((size_t)(b * NSEQ + qrow)) * CEMB + hh * HDIM + n2 * 16 + fr] =
                        f2bf(od[mi][n2][r] * inv);
            }
        }
}

// ---------------- generic 128x128 MFMA GEMM with epilogues
#define MODE_QKV  1
#define MODE_PROJ 3
#define MODE_FC1  4
#define MODE_FC2  5

struct GemmParams {
    const bf16* A;
    const bf16* Bt;
    int M, N, K;            // M,N %128==0; K%32==0
    int Mreal;
    float* Cf;
    bf16* Cb;
    const float* bias;
    const float* resid;
    bf16* qb; bf16* kb; bf16* vtb;
};

template<int MODE>
__global__ __launch_bounds__(256) void gemm128(GemmParams p) {
    __shared__ bf16 As[128 * 32];
    __shared__ bf16 Bs[128 * 32];
    const int tid  = threadIdx.x;
    const int lane = tid & 63;
    const int w    = tid >> 6;

    // bijective XCD swizzle (m204)
    const int nwg = gridDim.x * gridDim.y;
    const int lin = blockIdx.y * gridDim.x + blockIdx.x;
    const int q8 = nwg >> 3, r8 = nwg & 7;
    const int xcd = lin & 7, idx = lin >> 3;
    const int lin2 = ((xcd < r8) ? xcd * (q8 + 1) : r8 * (q8 + 1) + (xcd - r8) * q8) + idx;
    const int bm = (lin2 % gridDim.x) * 128;
    const int bn = (lin2 / gridDim.x) * 128;

    const bf16* A  = p.A;
    const bf16* Bt = p.Bt;
    const int wr = (w >> 1) * 64;
    const int wc = (w & 1) * 64;
    const int fr = lane & 15;
    const int fk = (lane >> 4) * 8;
    const int idx0 = w * 64 + lane;
    const int idx1 = idx0 + 256;
    const int r0 = idx0 >> 2, c0 = (idx0 & 3) * 8;
    const int r1 = idx1 >> 2, c1 = (idx1 & 3) * 8;

    f32x4 acc[4][4] = {};

    for (int k0 = 0; k0 < p.K; k0 += 32) {
        __syncthreads();
        GLOAD_LDS16(A  + (size_t)(bm + r0) * p.K + k0 + c0, As + (size_t)w * 512);
        GLOAD_LDS16(A  + (size_t)(bm + r1) * p.K + k0 + c1, As + (size_t)(w + 4) * 512);
        GLOAD_LDS16(Bt + (size_t)(bn + r0) * p.K + k0 + c0, Bs + (size_t)w * 512);
        GLOAD_LDS16(Bt + (size_t)(bn + r1) * p.K + k0 + c1, Bs + (size_t)(w + 4) * 512);
        __syncthreads();
        short8 a[4], b[4];
        #pragma unroll
        for (int m = 0; m < 4; m++)
            a[m] = *reinterpret_cast<const short8*>(&As[(wr + m * 16 + fr) * 32 + fk]);
        #pragma unroll
        for (int n = 0; n < 4; n++)
            b[n] = *reinterpret_cast<const short8*>(&Bs[(wc + n * 16 + fr) * 32 + fk]);
        #pragma unroll
        for (int m = 0; m < 4; m++)
            #pragma unroll
            for (int n = 0; n < 4; n++)
                acc[m][n] = __builtin_amdgcn_mfma_f32_16x16x32_bf16(a[m], b[n], acc[m][n], 0, 0, 0);
    }

    const int fq = (lane >> 4) * 4;
    const int colw = bn + wc;                 // wave-uniform column base (mult of 64)

    if (MODE == MODE_QKV) {
        // wave-uniform: which tensor + head (64-col span never crosses 768/64 boundary)
        const int which = colw / CEMB;
        const int hh = (colw - which * CEMB) >> 6;
        #pragma unroll
        for (int m = 0; m < 4; m++)
        #pragma unroll
        for (int r = 0; r < 4; r++) {
            int row = bm + wr + m * 16 + fq + r;
            if (row < p.Mreal) {
                int b2 = row / NSEQ;
                int n2 = row - b2 * NSEQ;
                size_t bh = (size_t)b2 * NHEADS + hh;
                if (which == 0) {
                    bf16* dst = p.qb + (bh * NP + n2) * HDIM + fr;
                    #pragma unroll
                    for (int n = 0; n < 4; n++) dst[n * 16] = f2bf(acc[m][n][r]);
                } else if (which == 1) {
                    bf16* dst = p.kb + (bh * NP + n2) * HDIM + fr;
                    #pragma unroll
                    for (int n = 0; n < 4; n++) dst[n * 16] = f2bf(acc[m][n][r]);
                } else {
                    bf16* dst = p.vtb + (bh * HDIM + fr) * NP + n2;
                    #pragma unroll
                    for (int n = 0; n < 4; n++) dst[(size_t)n * 16 * NP] = f2bf(acc[m][n][r]);
                }
            }
        }
    } else if (MODE == MODE_FC1) {
        const float* bp = p.bias + colw + fr;
        float bb[4];
        #pragma unroll
        for (int n = 0; n < 4; n++) bb[n] = bp[n * 16];
        #pragma unroll
        for (int m = 0; m < 4; m++)
        #pragma unroll
        for (int r = 0; r < 4; r++) {
            int row = bm + wr + m * 16 + fq + r;
            if (row < p.Mreal) {
                bf16* crow = p.Cb + (size_t)row * p.N + colw + fr;
                #pragma unroll
                for (int n = 0; n < 4; n++)
                    crow[n * 16] = f2bf(gelu_f(acc[m][n][r] + bb[n]));
            }
        }
    } else { // MODE_PROJ / MODE_FC2: fp32 out = val + bias + resid
        const float* bp = p.bias + colw + fr;
        float bb[4];
        #pragma unroll
        for (int n = 0; n < 4; n++) bb[n] = bp[n * 16];
        #pragma unroll
        for (int m = 0; m < 4; m++)
        #pragma unroll
        for (int r = 0; r < 4; r++) {
            int row = bm + wr + m * 16 + fq + r;
            if (row < p.Mreal) {
                float* crow = p.Cf + (size_t)row * p.N + colw + fr;
                const float* rrow = p.resid + (size_t)row * p.N + colw + fr;
                #pragma unroll
                for (int n = 0; n < 4; n++)
                    crow[n * 16] = acc[m][n][r] + bb[n] + rrow[n * 16];
            }
        }
    }
}

extern "C" void kernel_launch(void* const* d_in, const int* in_sizes, int n_in,
                              void* d_out, int out_size, void* d_ws, size_t ws_size,
                              hipStream_t stream) {
    const float* x      = (const float*)d_in[0];
    const float* ln1_g  = (const float*)d_in[1];
    const float* ln1_b  = (const float*)d_in[2];
    const float* w_qkv  = (const float*)d_in[3];
    const float* w_proj = (const float*)d_in[4];
    const float* b_proj = (const float*)d_in[5];
    const float* ln2_g  = (const float*)d_in[6];
    const float* ln2_b  = (const float*)d_in[7];
    const float* w_fc1  = (const float*)d_in[8];
    const float* b_fc1  = (const float*)d_in[9];
    const float* w_fc2  = (const float*)d_in[10];
    const float* b_fc2  = (const float*)d_in[11];
    float* out = (float*)d_out;

    char* ws = (char*)d_ws;
    auto al = [](size_t b){ return (b + 255) & ~(size_t)255; };
    size_t off = 0;
    auto take = [&](size_t b)->char* { char* p = ws + off; off += al(b); return p; };

    bf16* wqkvT  = (bf16*)take((size_t)2304 * 768 * 2);
    bf16* wprojT = (bf16*)take((size_t)768 * 768 * 2);
    bf16* wfc1T  = (bf16*)take((size_t)3072 * 768 * 2);
    bf16* wfc2T  = (bf16*)take((size_t)768 * 3072 * 2);
    bf16* h      = (bf16*)take((size_t)(NTOK + 128) * CEMB * 2);
    bf16* o      = (bf16*)take((size_t)(NTOK + 128) * CEMB * 2);
    size_t fixedEnd = off;

    const size_t qkvB = (size_t)NBH * NP * HDIM * 2;
    bf16* q_c  = (bf16*)(ws + fixedEnd);
    bf16* k_c  = (bf16*)(ws + fixedEnd + qkvB);
    bf16* vT_c = (bf16*)(ws + fixedEnd + 2 * qkvB);
    bf16* g_c  = (bf16*)(ws + fixedEnd);       // MLP reuses region

    transpose_w<<<(768 * 2304 + 255) / 256, 256, 0, stream>>>(w_qkv, wqkvT, 768, 2304);
    transpose_w<<<(768 * 768 + 255) / 256, 256, 0, stream>>>(w_proj, wprojT, 768, 768);
    transpose_w<<<(768 * 3072 + 255) / 256, 256, 0, stream>>>(w_fc1, wfc1T, 768, 3072);
    transpose_w<<<(3072 * 768 + 255) / 256, 256, 0, stream>>>(w_fc2, wfc2T, 3072, 768);

    ln_kernel<<<NTOK, 256, 0, stream>>>(x, ln1_g, ln1_b, h);

    {
        const int mPad = (NTOK + 127) & ~127;   // 36992
        GemmParams p{};
        p.A = h; p.Bt = wqkvT;
        p.M = mPad; p.N = 3 * CEMB; p.K = CEMB; p.Mreal = NTOK;
        p.qb = q_c; p.kb = k_c; p.vtb = vT_c;
        gemm128<MODE_QKV><<<dim3(mPad / 128, 3 * CEMB / 128), 256, 0, stream>>>(p);
    }

    flash_attn<<<dim3(NP / 128, NBH), 256, 0, stream>>>(q_c, k_c, vT_c, o);

    {
        const int mPad = (NTOK + 127) & ~127;
        GemmParams p{};
        p.A = o; p.Bt = wprojT;
        p.M = mPad; p.N = CEMB; p.K = CEMB; p.Mreal = NTOK;
        p.Cf = out; p.bias = b_proj; p.resid = x;
        gemm128<MODE_PROJ><<<dim3(mPad / 128, CEMB / 128), 256, 0, stream>>>(p);
    }

    ln_kernel<<<NTOK, 256, 0, stream>>>(out, ln2_g, ln2_b, h);

    {
        const int mPad = (NTOK + 127) & ~127;
        GemmParams p{};
        p.A = h; p.Bt = wfc1T;
        p.M = mPad; p.N = CHID; p.K = CEMB; p.Mreal = NTOK;
        p.Cb = g_c; p.bias = b_fc1;
        gemm128<MODE_FC1><<<dim3(mPad / 128, CHID / 128), 256, 0, stream>>>(p);
    }

    {
        const int mPad = (NTOK + 127) & ~127;
        GemmParams p{};
        p.A = g_c; p.Bt = wfc2T;
        p.M = mPad; p.N = CEMB; p.K = CHID; p.Mreal = NTOK;
        p.Cf = out; p.bias = b_fc2; p.resid = out;
        gemm128<MODE_FC2><<<dim3(mPad / 128, CEMB / 128), 256, 0, stream>>>(p);
    }
}

// Round 6
// 1404.090 us; speedup vs baseline: 1.8871x; 1.1372x over previous
//
#include <hip/hip_runtime.h>
#include <hip/hip_bf16.h>
#include <math.h>

using bf16 = __hip_bfloat16;
typedef __attribute__((ext_vector_type(8))) short short8;
typedef __attribute__((ext_vector_type(4))) float f32x4;

#define NSEQ   577
#define NBATCH 64
#define NTOK   36928   // 64*577
#define NHEADS 12
#define HDIM   64
#define NP     640     // padded seq len (multiple of 128)
#define CEMB   768
#define CHID   3072
#define NBH    (NBATCH*NHEADS)   // 768 head instances

__device__ __forceinline__ bf16 f2bf(float v){ return __float2bfloat16(v); }

// tanh-form GELU via one __expf; |err| vs exact ~1e-3, below bf16 rounding here.
__device__ __forceinline__ float gelu_f(float x) {
    float x3 = x * x * x;
    float y = 1.5957691216057308f * (x + 0.044715f * x3);
    float e = __expf(y);
    float t = 1.0f - 2.0f / (e + 1.0f);
    return 0.5f * x * (1.0f + t);
}

#define GLOAD_LDS16(gaddr, laddr) \
  __builtin_amdgcn_global_load_lds((__attribute__((address_space(1))) const void*)(gaddr), \
                                   (__attribute__((address_space(3))) void*)(laddr), 16, 0, 0)

// ---------------- weight convert+transpose: src fp32 [R][C] -> dst bf16 [C][R]
__global__ __launch_bounds__(256) void transpose_w(const float* __restrict__ src,
                                                   bf16* __restrict__ dst, int R, int C) {
    long idx = (long)blockIdx.x * 256 + threadIdx.x;
    long total = (long)R * C;
    if (idx < total) {
        int r = (int)(idx / C);
        int c = (int)(idx - (long)r * C);
        dst[(long)c * R + r] = f2bf(src[idx]);
    }
}

// ---------------- LayerNorm: fp32 [rows][768] -> bf16 [rows][768]
__global__ __launch_bounds__(256) void ln_kernel(const float* __restrict__ x,
                                                 const float* __restrict__ gamma,
                                                 const float* __restrict__ beta,
                                                 bf16* __restrict__ out) {
    int row = blockIdx.x;
    const float* xr = x + (size_t)row * CEMB;
    int tid = threadIdx.x;
    float v0 = xr[tid], v1 = xr[tid + 256], v2 = xr[tid + 512];
    float s = v0 + v1 + v2;
    #pragma unroll
    for (int o = 32; o > 0; o >>= 1) s += __shfl_down(s, o);
    __shared__ float red[4];
    if ((tid & 63) == 0) red[tid >> 6] = s;
    __syncthreads();
    float mean = (red[0] + red[1] + red[2] + red[3]) * (1.0f / CEMB);
    float d0 = v0 - mean, d1 = v1 - mean, d2 = v2 - mean;
    float q = d0*d0 + d1*d1 + d2*d2;
    #pragma unroll
    for (int o = 32; o > 0; o >>= 1) q += __shfl_down(q, o);
    __shared__ float red2[4];
    if ((tid & 63) == 0) red2[tid >> 6] = q;
    __syncthreads();
    float var = (red2[0] + red2[1] + red2[2] + red2[3]) * (1.0f / CEMB);
    float rs = rsqrtf(var + 1e-5f);
    bf16* orow = out + (size_t)row * CEMB;
    orow[tid]       = f2bf(d0 * rs * gamma[tid]       + beta[tid]);
    orow[tid + 256] = f2bf(d1 * rs * gamma[tid + 256] + beta[tid + 256]);
    orow[tid + 512] = f2bf(d2 * rs * gamma[tid + 512] + beta[tid + 512]);
}

// ---------------- fused flash attention ----------------
__global__ __launch_bounds__(256) void flash_attn(const bf16* __restrict__ qg,
                                                  const bf16* __restrict__ kg,
                                                  const bf16* __restrict__ vtg,
                                                  bf16* __restrict__ og) {
    const int tid = threadIdx.x, lane = tid & 63, w = tid >> 6;
    const int fr = lane & 15, fh = lane >> 4;
    const int bh = blockIdx.y;
    const int q0 = blockIdx.x * 128;
    const int wr = w * 32;

    __shared__ bf16 Ks[64 * 64];    // [key][d]
    __shared__ bf16 Vs[64 * 64];    // [d][key]
    __shared__ bf16 Ps[128 * 64];   // [qrow][key]

    const bf16* qb = qg  + (size_t)bh * NP * HDIM;
    const bf16* kb = kg  + (size_t)bh * NP * HDIM;
    const bf16* vb = vtg + (size_t)bh * HDIM * NP;

    short8 qa[2][2];
    #pragma unroll
    for (int mi = 0; mi < 2; mi++)
        #pragma unroll
        for (int ks = 0; ks < 2; ks++)
            qa[mi][ks] = *reinterpret_cast<const short8*>(
                qb + (size_t)(q0 + wr + mi * 16 + fr) * HDIM + ks * 32 + fh * 8);

    f32x4 od[2][4] = {};
    float m_run[2][4], l_run[2][4];
    #pragma unroll
    for (int mi = 0; mi < 2; mi++)
        #pragma unroll
        for (int r = 0; r < 4; r++) { m_run[mi][r] = -1e30f; l_run[mi][r] = 0.f; }

    for (int t = 0; t < NP / 64; t++) {
        const int kb0 = t * 64;
        __syncthreads();
        {
            const bf16* src = kb + (size_t)kb0 * HDIM;
            GLOAD_LDS16(src + w * 512 + lane * 8,        Ks + w * 512);
            GLOAD_LDS16(src + 2048 + w * 512 + lane * 8, Ks + 2048 + w * 512);
        }
        {
            int d0 = w * 8;
            GLOAD_LDS16(vb + (size_t)(d0 + (lane >> 3)) * NP + kb0 + (lane & 7) * 8,
                        Vs + d0 * 64);
            d0 = 32 + w * 8;
            GLOAD_LDS16(vb + (size_t)(d0 + (lane >> 3)) * NP + kb0 + (lane & 7) * 8,
                        Vs + d0 * 64);
        }
        __syncthreads();

        f32x4 sacc[2][4] = {};
        short8 kf[4][2];
        #pragma unroll
        for (int n = 0; n < 4; n++)
            #pragma unroll
            for (int ks = 0; ks < 2; ks++)
                kf[n][ks] = *reinterpret_cast<const short8*>(&Ks[(n * 16 + fr) * 64 + ks * 32 + fh * 8]);
        #pragma unroll
        for (int mi = 0; mi < 2; mi++)
            #pragma unroll
            for (int n = 0; n < 4; n++)
                #pragma unroll
                for (int ks = 0; ks < 2; ks++)
                    sacc[mi][n] = __builtin_amdgcn_mfma_f32_16x16x32_bf16(qa[mi][ks], kf[n][ks], sacc[mi][n], 0, 0, 0);

        #pragma unroll
        for (int mi = 0; mi < 2; mi++) {
            float sv[4][4];
            float tm[4] = {-1e30f, -1e30f, -1e30f, -1e30f};
            #pragma unroll
            for (int n = 0; n < 4; n++) {
                int col = kb0 + n * 16 + fr;
                bool valid = col < NSEQ;
                #pragma unroll
                for (int r = 0; r < 4; r++) {
                    float s = sacc[mi][n][r] * 0.125f;
                    sv[n][r] = valid ? s : -1e30f;
                    tm[r] = fmaxf(tm[r], sv[n][r]);
                }
            }
            #pragma unroll
            for (int r = 0; r < 4; r++) {
                #pragma unroll
                for (int o = 1; o < 16; o <<= 1) tm[r] = fmaxf(tm[r], __shfl_xor(tm[r], o));
                float mn = fmaxf(m_run[mi][r], tm[r]);
                float sc = __expf(m_run[mi][r] - mn);
                m_run[mi][r] = mn;
                float ps = 0.f;
                #pragma unroll
                for (int n = 0; n < 4; n++) {
                    float e = __expf(sv[n][r] - mn);
                    sv[n][r] = e; ps += e;
                }
                #pragma unroll
                for (int o = 1; o < 16; o <<= 1) ps += __shfl_xor(ps, o);
                l_run[mi][r] = l_run[mi][r] * sc + ps;
                #pragma unroll
                for (int n2 = 0; n2 < 4; n2++) od[mi][n2][r] *= sc;
            }
            #pragma unroll
            for (int n = 0; n < 4; n++)
                #pragma unroll
                for (int r = 0; r < 4; r++)
                    Ps[(wr + mi * 16 + fh * 4 + r) * 64 + n * 16 + fr] = f2bf(sv[n][r]);
        }
        __syncthreads();

        short8 pa[2][2], vf[4][2];
        #pragma unroll
        for (int mi = 0; mi < 2; mi++)
            #pragma unroll
            for (int ks = 0; ks < 2; ks++)
                pa[mi][ks] = *reinterpret_cast<const short8*>(&Ps[(wr + mi * 16 + fr) * 64 + ks * 32 + fh * 8]);
        #pragma unroll
        for (int n2 = 0; n2 < 4; n2++)
            #pragma unroll
            for (int ks = 0; ks < 2; ks++)
                vf[n2][ks] = *reinterpret_cast<const short8*>(&Vs[(n2 * 16 + fr) * 64 + ks * 32 + fh * 8]);
        #pragma unroll
        for (int mi = 0; mi < 2; mi++)
            #pragma unroll
            for (int n2 = 0; n2 < 4; n2++)
                #pragma unroll
                for (int ks = 0; ks < 2; ks++)
                    od[mi][n2] = __builtin_amdgcn_mfma_f32_16x16x32_bf16(pa[mi][ks], vf[n2][ks], od[mi][n2], 0, 0, 0);
    }

    const int b = bh / NHEADS, hh = bh - b * NHEADS;
    #pragma unroll
    for (int mi = 0; mi < 2; mi++)
        #pragma unroll
        for (int r = 0; r < 4; r++) {
            int qrow = q0 + wr + mi * 16 + fh * 4 + r;
            if (qrow < NSEQ) {
                float inv = 1.f / l_run[mi][r];
                #pragma unroll
                for (int n2 = 0; n2 < 4; n2++)
                    og[((size_t)(b * NSEQ + qrow)) * CEMB + hh * HDIM + n2 * 16 + fr] =
                        f2bf(od[mi][n2][r] * inv);
            }
        }
}

// ---------------- generic 128x128 MFMA GEMM, double-buffered prefetch
#define MODE_QKV  1
#define MODE_PROJ 3
#define MODE_FC1  4
#define MODE_FC2  5

struct GemmParams {
    const bf16* A;
    const bf16* Bt;
    int M, N, K;            // M,N %128==0; K%32==0 (K/32 even)
    int Mreal;
    float* Cf;
    bf16* Cb;
    const float* bias;
    const float* resid;
    bf16* qb; bf16* kb; bf16* vtb;
};

template<int MODE>
__global__ __launch_bounds__(256) void gemm128(GemmParams p) {
    __shared__ bf16 AsBuf[2][128 * 32];
    __shared__ bf16 BsBuf[2][128 * 32];
    const int tid  = threadIdx.x;
    const int lane = tid & 63;
    const int w    = tid >> 6;

    // A-major linearization + bijective XCD chunking: consecutive lin2 share
    // the A-row-panel, and each XCD gets a contiguous lin2 range -> A-panel
    // is fetched ~once per XCD L2 instead of once per block.
    const int gx = gridDim.x, gy = gridDim.y;
    const int nwg = gx * gy;
    const int orig = blockIdx.y * gx + blockIdx.x;
    const int q8 = nwg >> 3, r8 = nwg & 7;
    const int xcd = orig & 7, oid = orig >> 3;
    const int lin2 = ((xcd < r8) ? xcd * (q8 + 1) : r8 * (q8 + 1) + (xcd - r8) * q8) + oid;
    const int bm = (lin2 / gy) * 128;
    const int bn = (lin2 % gy) * 128;

    const int Kd = p.K;
    const int wr = (w >> 1) * 64;
    const int wc = (w & 1) * 64;
    const int fr = lane & 15;
    const int fk = (lane >> 4) * 8;
    const int idx0 = w * 64 + lane;
    const int idx1 = idx0 + 256;
    const int r0 = idx0 >> 2, c0 = (idx0 & 3) * 8;
    const int r1 = idx1 >> 2, c1 = (idx1 & 3) * 8;

    const bf16* aS0 = p.A  + (size_t)(bm + r0) * Kd + c0;
    const bf16* aS1 = p.A  + (size_t)(bm + r1) * Kd + c1;
    const bf16* bS0 = p.Bt + (size_t)(bn + r0) * Kd + c0;
    const bf16* bS1 = p.Bt + (size_t)(bn + r1) * Kd + c1;

    f32x4 acc[4][4] = {};

    bf16 *Ac = AsBuf[0], *An = AsBuf[1];
    bf16 *Bc = BsBuf[0], *Bn = BsBuf[1];

    auto stage = [&](bf16* Ad, bf16* Bd) {
        GLOAD_LDS16(aS0, Ad + (size_t)w * 512);
        GLOAD_LDS16(aS1, Ad + (size_t)(w + 4) * 512);
        GLOAD_LDS16(bS0, Bd + (size_t)w * 512);
        GLOAD_LDS16(bS1, Bd + (size_t)(w + 4) * 512);
        aS0 += 32; aS1 += 32; bS0 += 32; bS1 += 32;
    };
    auto compute = [&](const bf16* Ad, const bf16* Bd) {
        short8 a[4], b[4];
        #pragma unroll
        for (int m = 0; m < 4; m++)
            a[m] = *reinterpret_cast<const short8*>(&Ad[(wr + m * 16 + fr) * 32 + fk]);
        #pragma unroll
        for (int n = 0; n < 4; n++)
            b[n] = *reinterpret_cast<const short8*>(&Bd[(wc + n * 16 + fr) * 32 + fk]);
        #pragma unroll
        for (int m = 0; m < 4; m++)
            #pragma unroll
            for (int n = 0; n < 4; n++)
                acc[m][n] = __builtin_amdgcn_mfma_f32_16x16x32_bf16(a[m], b[n], acc[m][n], 0, 0, 0);
    };

    const int T = Kd >> 5;
    stage(Ac, Bc);
    __syncthreads();                     // vmcnt(0) drain + barrier: buf0 ready
    for (int t = 1; t < T; ++t) {
        stage(An, Bn);                   // issue next tile's loads (in flight during compute)
        compute(Ac, Bc);
        __syncthreads();                 // readers of Ac/Bc done + An/Bn published
        bf16* tp;
        tp = Ac; Ac = An; An = tp;
        tp = Bc; Bc = Bn; Bn = tp;
    }
    compute(Ac, Bc);

    const int fq = (lane >> 4) * 4;
    const int colw = bn + wc;            // wave-uniform column base (mult of 64)

    if (MODE == MODE_QKV) {
        const int which = colw / CEMB;
        const int hh = (colw - which * CEMB) >> 6;
        #pragma unroll
        for (int m = 0; m < 4; m++)
        #pragma unroll
        for (int r = 0; r < 4; r++) {
            int row = bm + wr + m * 16 + fq + r;
            if (row < p.Mreal) {
                int b2 = row / NSEQ;
                int n2 = row - b2 * NSEQ;
                size_t bh = (size_t)b2 * NHEADS + hh;
                if (which == 0) {
                    bf16* dst = p.qb + (bh * NP + n2) * HDIM + fr;
                    #pragma unroll
                    for (int n = 0; n < 4; n++) dst[n * 16] = f2bf(acc[m][n][r]);
                } else if (which == 1) {
                    bf16* dst = p.kb + (bh * NP + n2) * HDIM + fr;
                    #pragma unroll
                    for (int n = 0; n < 4; n++) dst[n * 16] = f2bf(acc[m][n][r]);
                } else {
                    bf16* dst = p.vtb + (bh * HDIM + fr) * NP + n2;
                    #pragma unroll
                    for (int n = 0; n < 4; n++) dst[(size_t)n * 16 * NP] = f2bf(acc[m][n][r]);
                }
            }
        }
    } else if (MODE == MODE_FC1) {
        const float* bp = p.bias + colw + fr;
        float bb[4];
        #pragma unroll
        for (int n = 0; n < 4; n++) bb[n] = bp[n * 16];
        #pragma unroll
        for (int m = 0; m < 4; m++)
        #pragma unroll
        for (int r = 0; r < 4; r++) {
            int row = bm + wr + m * 16 + fq + r;
            if (row < p.Mreal) {
                bf16* crow = p.Cb + (size_t)row * p.N + colw + fr;
                #pragma unroll
                for (int n = 0; n < 4; n++)
                    crow[n * 16] = f2bf(gelu_f(acc[m][n][r] + bb[n]));
            }
        }
    } else { // MODE_PROJ / MODE_FC2: fp32 out = val + bias + resid
        const float* bp = p.bias + colw + fr;
        float bb[4];
        #pragma unroll
        for (int n = 0; n < 4; n++) bb[n] = bp[n * 16];
        #pragma unroll
        for (int m = 0; m < 4; m++)
        #pragma unroll
        for (int r = 0; r < 4; r++) {
            int row = bm + wr + m * 16 + fq + r;
            if (row < p.Mreal) {
                float* crow = p.Cf + (size_t)row * p.N + colw + fr;
                const float* rrow = p.resid + (size_t)row * p.N + colw + fr;
                #pragma unroll
                for (int n = 0; n < 4; n++)
                    crow[n * 16] = acc[m][n][r] + bb[n] + rrow[n * 16];
            }
        }
    }
}

extern "C" void kernel_launch(void* const* d_in, const int* in_sizes, int n_in,
                              void* d_out, int out_size, void* d_ws, size_t ws_size,
                              hipStream_t stream) {
    const float* x      = (const float*)d_in[0];
    const float* ln1_g  = (const float*)d_in[1];
    const float* ln1_b  = (const float*)d_in[2];
    const float* w_qkv  = (const float*)d_in[3];
    const float* w_proj = (const float*)d_in[4];
    const float* b_proj = (const float*)d_in[5];
    const float* ln2_g  = (const float*)d_in[6];
    const float* ln2_b  = (const float*)d_in[7];
    const float* w_fc1  = (const float*)d_in[8];
    const float* b_fc1  = (const float*)d_in[9];
    const float* w_fc2  = (const float*)d_in[10];
    const float* b_fc2  = (const float*)d_in[11];
    float* out = (float*)d_out;

    char* ws = (char*)d_ws;
    auto al = [](size_t b){ return (b + 255) & ~(size_t)255; };
    size_t off = 0;
    auto take = [&](size_t b)->char* { char* p = ws + off; off += al(b); return p; };

    bf16* wqkvT  = (bf16*)take((size_t)2304 * 768 * 2);
    bf16* wprojT = (bf16*)take((size_t)768 * 768 * 2);
    bf16* wfc1T  = (bf16*)take((size_t)3072 * 768 * 2);
    bf16* wfc2T  = (bf16*)take((size_t)768 * 3072 * 2);
    bf16* h      = (bf16*)take((size_t)(NTOK + 128) * CEMB * 2);
    bf16* o      = (bf16*)take((size_t)(NTOK + 128) * CEMB * 2);
    size_t fixedEnd = off;

    const size_t qkvB = (size_t)NBH * NP * HDIM * 2;
    bf16* q_c  = (bf16*)(ws + fixedEnd);
    bf16* k_c  = (bf16*)(ws + fixedEnd + qkvB);
    bf16* vT_c = (bf16*)(ws + fixedEnd + 2 * qkvB);
    bf16* g_c  = (bf16*)(ws + fixedEnd);       // MLP reuses region

    transpose_w<<<(768 * 2304 + 255) / 256, 256, 0, stream>>>(w_qkv, wqkvT, 768, 2304);
    transpose_w<<<(768 * 768 + 255) / 256, 256, 0, stream>>>(w_proj, wprojT, 768, 768);
    transpose_w<<<(768 * 3072 + 255) / 256, 256, 0, stream>>>(w_fc1, wfc1T, 768, 3072);
    transpose_w<<<(3072 * 768 + 255) / 256, 256, 0, stream>>>(w_fc2, wfc2T, 3072, 768);

    ln_kernel<<<NTOK, 256, 0, stream>>>(x, ln1_g, ln1_b, h);

    {
        const int mPad = (NTOK + 127) & ~127;   // 36992
        GemmParams p{};
        p.A = h; p.Bt = wqkvT;
        p.M = mPad; p.N = 3 * CEMB; p.K = CEMB; p.Mreal = NTOK;
        p.qb = q_c; p.kb = k_c; p.vtb = vT_c;
        gemm128<MODE_QKV><<<dim3(mPad / 128, 3 * CEMB / 128), 256, 0, stream>>>(p);
    }

    flash_attn<<<dim3(NP / 128, NBH), 256, 0, stream>>>(q_c, k_c, vT_c, o);

    {
        const int mPad = (NTOK + 127) & ~127;
        GemmParams p{};
        p.A = o; p.Bt = wprojT;
        p.M = mPad; p.N = CEMB; p.K = CEMB; p.Mreal = NTOK;
        p.Cf = out; p.bias = b_proj; p.resid = x;
        gemm128<MODE_PROJ><<<dim3(mPad / 128, CEMB / 128), 256, 0, stream>>>(p);
    }

    ln_kernel<<<NTOK, 256, 0, stream>>>(out, ln2_g, ln2_b, h);

    {
        const int mPad = (NTOK + 127) & ~127;
        GemmParams p{};
        p.A = h; p.Bt = wfc1T;
        p.M = mPad; p.N = CHID; p.K = CEMB; p.Mreal = NTOK;
        p.Cb = g_c; p.bias = b_fc1;
        gemm128<MODE_FC1><<<dim3(mPad / 128, CHID / 128), 256, 0, stream>>>(p);
    }

    {
        const int mPad = (NTOK + 127) & ~127;
        GemmParams p{};
        p.A = g_c; p.Bt = wfc2T;
        p.M = mPad; p.N = CEMB; p.K = CHID; p.Mreal = NTOK;
        p.Cf = out; p.bias = b_fc2; p.resid = out;
        gemm128<MODE_FC2><<<dim3(mPad / 128, CEMB / 128), 256, 0, stream>>>(p);
    }
}

// Round 7
// 1376.622 us; speedup vs baseline: 1.9248x; 1.0200x over previous
//
#include <hip/hip_runtime.h>
#include <hip/hip_bf16.h>
#include <math.h>

using bf16 = __hip_bfloat16;
typedef __attribute__((ext_vector_type(8))) short short8;
typedef __attribute__((ext_vector_type(4))) float f32x4;

#define NSEQ   577
#define NBATCH 64
#define NTOK   36928   // 64*577
#define MPAD   37120   // NTOK padded to multiple of 256
#define NHEADS 12
#define HDIM   64
#define NP     640     // padded seq len (multiple of 128)
#define CEMB   768
#define CHID   3072
#define NBH    (NBATCH*NHEADS)   // 768 head instances

__device__ __forceinline__ bf16 f2bf(float v){ return __float2bfloat16(v); }

// tanh-form GELU via one __expf; |err| vs exact ~1e-3, below bf16 rounding here.
__device__ __forceinline__ float gelu_f(float x) {
    float x3 = x * x * x;
    float y = 1.5957691216057308f * (x + 0.044715f * x3);
    float e = __expf(y);
    float t = 1.0f - 2.0f / (e + 1.0f);
    return 0.5f * x * (1.0f + t);
}

#define GLOAD_LDS16(gaddr, laddr) \
  __builtin_amdgcn_global_load_lds((__attribute__((address_space(1))) const void*)(gaddr), \
                                   (__attribute__((address_space(3))) void*)(laddr), 16, 0, 0)

// ---------------- weight convert+transpose: src fp32 [R][C] -> dst bf16 [C][R]
__global__ __launch_bounds__(256) void transpose_w(const float* __restrict__ src,
                                                   bf16* __restrict__ dst, int R, int C) {
    long idx = (long)blockIdx.x * 256 + threadIdx.x;
    long total = (long)R * C;
    if (idx < total) {
        int r = (int)(idx / C);
        int c = (int)(idx - (long)r * C);
        dst[(long)c * R + r] = f2bf(src[idx]);
    }
}

// ---------------- LayerNorm: fp32 [rows][768] -> bf16 [rows][768]
__global__ __launch_bounds__(256) void ln_kernel(const float* __restrict__ x,
                                                 const float* __restrict__ gamma,
                                                 const float* __restrict__ beta,
                                                 bf16* __restrict__ out) {
    int row = blockIdx.x;
    const float* xr = x + (size_t)row * CEMB;
    int tid = threadIdx.x;
    float v0 = xr[tid], v1 = xr[tid + 256], v2 = xr[tid + 512];
    float s = v0 + v1 + v2;
    #pragma unroll
    for (int o = 32; o > 0; o >>= 1) s += __shfl_down(s, o);
    __shared__ float red[4];
    if ((tid & 63) == 0) red[tid >> 6] = s;
    __syncthreads();
    float mean = (red[0] + red[1] + red[2] + red[3]) * (1.0f / CEMB);
    float d0 = v0 - mean, d1 = v1 - mean, d2 = v2 - mean;
    float q = d0*d0 + d1*d1 + d2*d2;
    #pragma unroll
    for (int o = 32; o > 0; o >>= 1) q += __shfl_down(q, o);
    __shared__ float red2[4];
    if ((tid & 63) == 0) red2[tid >> 6] = q;
    __syncthreads();
    float var = (red2[0] + red2[1] + red2[2] + red2[3]) * (1.0f / CEMB);
    float rs = rsqrtf(var + 1e-5f);
    bf16* orow = out + (size_t)row * CEMB;
    orow[tid]       = f2bf(d0 * rs * gamma[tid]       + beta[tid]);
    orow[tid + 256] = f2bf(d1 * rs * gamma[tid + 256] + beta[tid + 256]);
    orow[tid + 512] = f2bf(d2 * rs * gamma[tid + 512] + beta[tid + 512]);
}

// ---------------- fused flash attention ----------------
// q is pre-scaled by 1/8 at the QKV epilogue.
__global__ __launch_bounds__(256) void flash_attn(const bf16* __restrict__ qg,
                                                  const bf16* __restrict__ kg,
                                                  const bf16* __restrict__ vtg,
                                                  bf16* __restrict__ og) {
    const int tid = threadIdx.x, lane = tid & 63, w = tid >> 6;
    const int fr = lane & 15, fh = lane >> 4;
    const int bh = blockIdx.y;
    const int q0 = blockIdx.x * 128;
    const int wr = w * 32;

    __shared__ bf16 Ks[64 * 64];    // [key][d]
    __shared__ bf16 Vs[64 * 64];    // [d][key]
    __shared__ bf16 Ps[128 * 64];   // [qrow][key]

    const bf16* qb = qg  + (size_t)bh * NP * HDIM;
    const bf16* kb = kg  + (size_t)bh * NP * HDIM;
    const bf16* vb = vtg + (size_t)bh * HDIM * NP;

    short8 qa[2][2];
    #pragma unroll
    for (int mi = 0; mi < 2; mi++)
        #pragma unroll
        for (int ks = 0; ks < 2; ks++)
            qa[mi][ks] = *reinterpret_cast<const short8*>(
                qb + (size_t)(q0 + wr + mi * 16 + fr) * HDIM + ks * 32 + fh * 8);

    f32x4 od[2][4] = {};
    float m_run[2][4], l_run[2][4];
    #pragma unroll
    for (int mi = 0; mi < 2; mi++)
        #pragma unroll
        for (int r = 0; r < 4; r++) { m_run[mi][r] = -1e30f; l_run[mi][r] = 0.f; }

    for (int t = 0; t < NP / 64; t++) {
        const int kb0 = t * 64;
        __syncthreads();
        {
            const bf16* src = kb + (size_t)kb0 * HDIM;
            GLOAD_LDS16(src + w * 512 + lane * 8,        Ks + w * 512);
            GLOAD_LDS16(src + 2048 + w * 512 + lane * 8, Ks + 2048 + w * 512);
        }
        {
            int d0 = w * 8;
            GLOAD_LDS16(vb + (size_t)(d0 + (lane >> 3)) * NP + kb0 + (lane & 7) * 8,
                        Vs + d0 * 64);
            d0 = 32 + w * 8;
            GLOAD_LDS16(vb + (size_t)(d0 + (lane >> 3)) * NP + kb0 + (lane & 7) * 8,
                        Vs + d0 * 64);
        }
        __syncthreads();

        f32x4 sacc[2][4] = {};
        short8 kf[4][2];
        #pragma unroll
        for (int n = 0; n < 4; n++)
            #pragma unroll
            for (int ks = 0; ks < 2; ks++)
                kf[n][ks] = *reinterpret_cast<const short8*>(&Ks[(n * 16 + fr) * 64 + ks * 32 + fh * 8]);
        #pragma unroll
        for (int mi = 0; mi < 2; mi++)
            #pragma unroll
            for (int n = 0; n < 4; n++)
                #pragma unroll
                for (int ks = 0; ks < 2; ks++)
                    sacc[mi][n] = __builtin_amdgcn_mfma_f32_16x16x32_bf16(qa[mi][ks], kf[n][ks], sacc[mi][n], 0, 0, 0);

        #pragma unroll
        for (int mi = 0; mi < 2; mi++) {
            float sv[4][4];
            float tm[4] = {-1e30f, -1e30f, -1e30f, -1e30f};
            #pragma unroll
            for (int n = 0; n < 4; n++) {
                int col = kb0 + n * 16 + fr;
                bool valid = col < NSEQ;
                #pragma unroll
                for (int r = 0; r < 4; r++) {
                    float s = sacc[mi][n][r];        // q pre-scaled
                    sv[n][r] = valid ? s : -1e30f;
                    tm[r] = fmaxf(tm[r], sv[n][r]);
                }
            }
            #pragma unroll
            for (int r = 0; r < 4; r++) {
                #pragma unroll
                for (int o = 1; o < 16; o <<= 1) tm[r] = fmaxf(tm[r], __shfl_xor(tm[r], o));
                float mn = fmaxf(m_run[mi][r], tm[r]);
                float sc = __expf(m_run[mi][r] - mn);
                m_run[mi][r] = mn;
                float ps = 0.f;
                #pragma unroll
                for (int n = 0; n < 4; n++) {
                    float e = __expf(sv[n][r] - mn);
                    sv[n][r] = e; ps += e;
                }
                #pragma unroll
                for (int o = 1; o < 16; o <<= 1) ps += __shfl_xor(ps, o);
                l_run[mi][r] = l_run[mi][r] * sc + ps;
                #pragma unroll
                for (int n2 = 0; n2 < 4; n2++) od[mi][n2][r] *= sc;
            }
            #pragma unroll
            for (int n = 0; n < 4; n++)
                #pragma unroll
                for (int r = 0; r < 4; r++)
                    Ps[(wr + mi * 16 + fh * 4 + r) * 64 + n * 16 + fr] = f2bf(sv[n][r]);
        }
        __syncthreads();

        short8 pa[2][2], vf[4][2];
        #pragma unroll
        for (int mi = 0; mi < 2; mi++)
            #pragma unroll
            for (int ks = 0; ks < 2; ks++)
                pa[mi][ks] = *reinterpret_cast<const short8*>(&Ps[(wr + mi * 16 + fr) * 64 + ks * 32 + fh * 8]);
        #pragma unroll
        for (int n2 = 0; n2 < 4; n2++)
            #pragma unroll
            for (int ks = 0; ks < 2; ks++)
                vf[n2][ks] = *reinterpret_cast<const short8*>(&Vs[(n2 * 16 + fr) * 64 + ks * 32 + fh * 8]);
        #pragma unroll
        for (int mi = 0; mi < 2; mi++)
            #pragma unroll
            for (int n2 = 0; n2 < 4; n2++)
                #pragma unroll
                for (int ks = 0; ks < 2; ks++)
                    od[mi][n2] = __builtin_amdgcn_mfma_f32_16x16x32_bf16(pa[mi][ks], vf[n2][ks], od[mi][n2], 0, 0, 0);
    }

    const int b = bh / NHEADS, hh = bh - b * NHEADS;
    #pragma unroll
    for (int mi = 0; mi < 2; mi++)
        #pragma unroll
        for (int r = 0; r < 4; r++) {
            int qrow = q0 + wr + mi * 16 + fh * 4 + r;
            if (qrow < NSEQ) {
                float inv = 1.f / l_run[mi][r];
                #pragma unroll
                for (int n2 = 0; n2 < 4; n2++)
                    og[((size_t)(b * NSEQ + qrow)) * CEMB + hh * HDIM + n2 * 16 + fr] =
                        f2bf(od[mi][n2][r] * inv);
            }
        }
}

// ---------------- 256x256 tile, BK=64, 8 waves, double-buffered prefetch
#define MODE_QKV  1
#define MODE_PROJ 3
#define MODE_FC1  4
#define MODE_FC2  5

struct GemmParams {
    const bf16* A;
    const bf16* Bt;
    int M, N, K;            // M,N %256==0; K%64==0
    int Mreal;
    float* Cf;
    bf16* Cb;
    const float* bias;
    const float* resid;
    bf16* qb; bf16* kb; bf16* vtb;
};

template<int MODE>
__global__ __launch_bounds__(512, 2) void gemm256(GemmParams p) {
    __shared__ bf16 AsBuf[2][256 * 64];   // 32KB each
    __shared__ bf16 BsBuf[2][256 * 64];
    const int tid  = threadIdx.x;
    const int lane = tid & 63;
    const int w    = tid >> 6;           // 0..7

    // A-major linearization + bijective XCD chunking (m204)
    const int gx = gridDim.x, gy = gridDim.y;
    const int nwg = gx * gy;
    const int orig = blockIdx.y * gx + blockIdx.x;
    const int q8 = nwg >> 3, r8 = nwg & 7;
    const int xcd = orig & 7, oid = orig >> 3;
    const int lin2 = ((xcd < r8) ? xcd * (q8 + 1) : r8 * (q8 + 1) + (xcd - r8) * q8) + oid;
    const int bm = (lin2 / gy) * 256;
    const int bn = (lin2 % gy) * 256;

    const int Kd = p.K;
    const int wm = w >> 2, wn = w & 3;   // 2M x 4N wave grid
    const int wr = wm * 128, wc = wn * 64;
    const int fr = lane & 15;
    const int fk = (lane >> 4) * 8;

    // staging: tile [256][64] bf16 = 32KB = 4 steps x (512 thr x 16B)
    // step s: byte off = s*8192 + w*1024 + lane*16 -> row = s*64 + w*8 + lane/8, col = (lane&7)*8
    const int sr = w * 8 + (lane >> 3);
    const int sc = (lane & 7) * 8;
    const bf16* aS[4]; const bf16* bS[4];
    #pragma unroll
    for (int s = 0; s < 4; s++) {
        aS[s] = p.A  + (size_t)(bm + s * 64 + sr) * Kd + sc;
        bS[s] = p.Bt + (size_t)(bn + s * 64 + sr) * Kd + sc;
    }

    f32x4 acc[8][4] = {};
    bf16 *Ac = AsBuf[0], *An = AsBuf[1], *Bc = BsBuf[0], *Bn = BsBuf[1];

    auto stage = [&](bf16* Ad, bf16* Bd) {
        #pragma unroll
        for (int s = 0; s < 4; s++) {
            GLOAD_LDS16(aS[s], Ad + (size_t)(s * 8 + w) * 512);
            GLOAD_LDS16(bS[s], Bd + (size_t)(s * 8 + w) * 512);
            aS[s] += 64; bS[s] += 64;
        }
    };
    auto compute = [&](const bf16* Ad, const bf16* Bd) {
        #pragma unroll
        for (int ks = 0; ks < 2; ks++) {
            short8 b[4];
            #pragma unroll
            for (int n = 0; n < 4; n++)
                b[n] = *reinterpret_cast<const short8*>(&Bd[(wc + n * 16 + fr) * 64 + ks * 32 + fk]);
            #pragma unroll
            for (int m = 0; m < 8; m++) {
                short8 a = *reinterpret_cast<const short8*>(&Ad[(wr + m * 16 + fr) * 64 + ks * 32 + fk]);
                #pragma unroll
                for (int n = 0; n < 4; n++)
                    acc[m][n] = __builtin_amdgcn_mfma_f32_16x16x32_bf16(a, b[n], acc[m][n], 0, 0, 0);
            }
        }
    };

    const int T = Kd >> 6;
    stage(Ac, Bc);
    __syncthreads();                     // vmcnt(0) drain + barrier: buf0 ready
    for (int t = 1; t < T; ++t) {
        stage(An, Bn);                   // next K-tile's loads in flight during compute
        compute(Ac, Bc);
        __syncthreads();                 // readers of cur done + next published
        bf16* tp;
        tp = Ac; Ac = An; An = tp;
        tp = Bc; Bc = Bn; Bn = tp;
    }
    compute(Ac, Bc);

    const int fq = (lane >> 4) * 4;
    const int colw = bn + wc;            // wave-uniform column base (mult of 64)

    if (MODE == MODE_QKV) {
        const int which = colw / CEMB;   // wave-uniform (64-col span never crosses 768/64)
        const int hh = (colw - which * CEMB) >> 6;
        const float scl = (which == 0) ? 0.125f : 1.0f;   // fold attention scale into q
        #pragma unroll
        for (int m = 0; m < 8; m++)
        #pragma unroll
        for (int r = 0; r < 4; r++) {
            int row = bm + wr + m * 16 + fq + r;
            if (row < p.Mreal) {
                int b2 = row / NSEQ;
                int n2 = row - b2 * NSEQ;
                size_t bh = (size_t)b2 * NHEADS + hh;
                if (which == 0) {
                    bf16* dst = p.qb + (bh * NP + n2) * HDIM + fr;
                    #pragma unroll
                    for (int n = 0; n < 4; n++) dst[n * 16] = f2bf(acc[m][n][r] * scl);
                } else if (which == 1) {
                    bf16* dst = p.kb + (bh * NP + n2) * HDIM + fr;
                    #pragma unroll
                    for (int n = 0; n < 4; n++) dst[n * 16] = f2bf(acc[m][n][r]);
                } else {
                    bf16* dst = p.vtb + (bh * HDIM + fr) * NP + n2;
                    #pragma unroll
                    for (int n = 0; n < 4; n++) dst[(size_t)n * 16 * NP] = f2bf(acc[m][n][r]);
                }
            }
        }
    } else if (MODE == MODE_FC1) {
        const float* bp = p.bias + colw + fr;
        float bb[4];
        #pragma unroll
        for (int n = 0; n < 4; n++) bb[n] = bp[n * 16];
        #pragma unroll
        for (int m = 0; m < 8; m++)
        #pragma unroll
        for (int r = 0; r < 4; r++) {
            int row = bm + wr + m * 16 + fq + r;
            if (row < p.Mreal) {
                bf16* crow = p.Cb + (size_t)row * p.N + colw + fr;
                #pragma unroll
                for (int n = 0; n < 4; n++)
                    crow[n * 16] = f2bf(gelu_f(acc[m][n][r] + bb[n]));
            }
        }
    } else { // MODE_PROJ / MODE_FC2: fp32 out = val + bias + resid
        const float* bp = p.bias + colw + fr;
        float bb[4];
        #pragma unroll
        for (int n = 0; n < 4; n++) bb[n] = bp[n * 16];
        #pragma unroll
        for (int m = 0; m < 8; m++)
        #pragma unroll
        for (int r = 0; r < 4; r++) {
            int row = bm + wr + m * 16 + fq + r;
            if (row < p.Mreal) {
                float* crow = p.Cf + (size_t)row * p.N + colw + fr;
                const float* rrow = p.resid + (size_t)row * p.N + colw + fr;
                #pragma unroll
                for (int n = 0; n < 4; n++)
                    crow[n * 16] = acc[m][n][r] + bb[n] + rrow[n * 16];
            }
        }
    }
}

extern "C" void kernel_launch(void* const* d_in, const int* in_sizes, int n_in,
                              void* d_out, int out_size, void* d_ws, size_t ws_size,
                              hipStream_t stream) {
    const float* x      = (const float*)d_in[0];
    const float* ln1_g  = (const float*)d_in[1];
    const float* ln1_b  = (const float*)d_in[2];
    const float* w_qkv  = (const float*)d_in[3];
    const float* w_proj = (const float*)d_in[4];
    const float* b_proj = (const float*)d_in[5];
    const float* ln2_g  = (const float*)d_in[6];
    const float* ln2_b  = (const float*)d_in[7];
    const float* w_fc1  = (const float*)d_in[8];
    const float* b_fc1  = (const float*)d_in[9];
    const float* w_fc2  = (const float*)d_in[10];
    const float* b_fc2  = (const float*)d_in[11];
    float* out = (float*)d_out;

    char* ws = (char*)d_ws;
    auto al = [](size_t b){ return (b + 255) & ~(size_t)255; };
    size_t off = 0;
    auto take = [&](size_t b)->char* { char* p = ws + off; off += al(b); return p; };

    bf16* wqkvT  = (bf16*)take((size_t)2304 * 768 * 2);
    bf16* wprojT = (bf16*)take((size_t)768 * 768 * 2);
    bf16* wfc1T  = (bf16*)take((size_t)3072 * 768 * 2);
    bf16* wfc2T  = (bf16*)take((size_t)768 * 3072 * 2);
    bf16* h      = (bf16*)take((size_t)MPAD * CEMB * 2);   // MPAD rows (pad = finite poison)
    bf16* o      = (bf16*)take((size_t)MPAD * CEMB * 2);
    size_t fixedEnd = off;

    const size_t qkvB = (size_t)NBH * NP * HDIM * 2;
    bf16* q_c  = (bf16*)(ws + fixedEnd);
    bf16* k_c  = (bf16*)(ws + fixedEnd + qkvB);
    bf16* vT_c = (bf16*)(ws + fixedEnd + 2 * qkvB);
    bf16* g_c  = (bf16*)(ws + fixedEnd);       // MLP reuses region: MPAD x 3072 bf16

    transpose_w<<<(768 * 2304 + 255) / 256, 256, 0, stream>>>(w_qkv, wqkvT, 768, 2304);
    transpose_w<<<(768 * 768 + 255) / 256, 256, 0, stream>>>(w_proj, wprojT, 768, 768);
    transpose_w<<<(768 * 3072 + 255) / 256, 256, 0, stream>>>(w_fc1, wfc1T, 768, 3072);
    transpose_w<<<(3072 * 768 + 255) / 256, 256, 0, stream>>>(w_fc2, wfc2T, 3072, 768);

    ln_kernel<<<NTOK, 256, 0, stream>>>(x, ln1_g, ln1_b, h);

    {
        GemmParams p{};
        p.A = h; p.Bt = wqkvT;
        p.M = MPAD; p.N = 3 * CEMB; p.K = CEMB; p.Mreal = NTOK;
        p.qb = q_c; p.kb = k_c; p.vtb = vT_c;
        gemm256<MODE_QKV><<<dim3(MPAD / 256, 3 * CEMB / 256), 512, 0, stream>>>(p);
    }

    flash_attn<<<dim3(NP / 128, NBH), 256, 0, stream>>>(q_c, k_c, vT_c, o);

    {
        GemmParams p{};
        p.A = o; p.Bt = wprojT;
        p.M = MPAD; p.N = CEMB; p.K = CEMB; p.Mreal = NTOK;
        p.Cf = out; p.bias = b_proj; p.resid = x;
        gemm256<MODE_PROJ><<<dim3(MPAD / 256, CEMB / 256), 512, 0, stream>>>(p);
    }

    ln_kernel<<<NTOK, 256, 0, stream>>>(out, ln2_g, ln2_b, h);

    {
        GemmParams p{};
        p.A = h; p.Bt = wfc1T;
        p.M = MPAD; p.N = CHID; p.K = CEMB; p.Mreal = NTOK;
        p.Cb = g_c; p.bias = b_fc1;
        gemm256<MODE_FC1><<<dim3(MPAD / 256, CHID / 256), 512, 0, stream>>>(p);
    }

    {
        GemmParams p{};
        p.A = g_c; p.Bt = wfc2T;
        p.M = MPAD; p.N = CEMB; p.K = CHID; p.Mreal = NTOK;
        p.Cf = out; p.bias = b_fc2; p.resid = out;
        gemm256<MODE_FC2><<<dim3(MPAD / 256, CEMB / 256), 512, 0, stream>>>(p);
    }
}